// Round 19
// baseline (209.053 us; speedup 1.0000x reference)
//
#include <hip/hip_runtime.h>

typedef unsigned short u16;
typedef unsigned long long u64;

#define BATCH  4
#define NSEQ   2048
#define DMODEL 512
#define TOK    8192   // BATCH*NSEQ

typedef __attribute__((ext_vector_type(8))) __bf16 bf16x8;
typedef __attribute__((ext_vector_type(4))) float f32x4;

__device__ __forceinline__ float bf2f(u16 u) {
    unsigned int x = ((unsigned int)u) << 16;
    return __uint_as_float(x);
}
__device__ __forceinline__ u16 f2bf(float f) {
    unsigned int x = __float_as_uint(f);
    unsigned int r = (x + 0x7FFFu + ((x >> 16) & 1u)) >> 16;  // RNE
    return (u16)r;
}
// dual-dtype load: flag!=0 -> input tensors are fp32, else bf16
__device__ __forceinline__ float ldf(const void* p, size_t i, bool f32) {
    return f32 ? ((const float*)p)[i] : bf2f(((const u16*)p)[i]);
}
// dual-dtype store to d_out (IO dtypes are coupled: fp32 in => fp32 out)
__device__ __forceinline__ void stf(void* p, size_t i, float v, bool f32) {
    if (f32) ((float*)p)[i] = v;
    else     ((u16*)p)[i] = f2bf(v);
}
// nested dim for compacted position p within a batch (groups e3|e2|e1|e0)
__device__ __forceinline__ int dt_of_pos(int p) {
    return (p < 256) ? 512 : (p < 512) ? 256 : (p < 1024) ? 128 : 64;
}

// ---------------------------------------------------------------------------
// Input dtype detection (fp32 confirmed by round 3; kept for robustness).
__global__ void detect_kernel(const u16* __restrict__ x, int* __restrict__ flag) {
    __shared__ int cnt;
    if (threadIdx.x == 0) cnt = 0;
    __syncthreads();
    int sane = 0;
    for (int i = threadIdx.x; i < 2048; i += blockDim.x) {
        u16 u = x[2 * i];
        int e = (u >> 7) & 0xFF;
        if (u == 0 || (e >= 100 && e <= 140)) sane++;
    }
    atomicAdd(&cnt, sane);
    __syncthreads();
    if (threadIdx.x == 0) *flag = (cnt >= 1024) ? 0 : 1;  // 1 => fp32 inputs
}

// ---------------------------------------------------------------------------
// Fused prep: blocks [0,3072) = weight convert+transpose (4 weights,
// [K][N] -> bf16 [N][K]); blocks [3072,5120) = router fp64 logits+softmax
// (one wave per token). The two halves have disjoint inputs and overlap.
__global__ __launch_bounds__(256) void prep_kernel(
    const void* __restrict__ wqkv, const void* __restrict__ wo,
    const void* __restrict__ w1, const void* __restrict__ w2,
    const void* __restrict__ xg, const void* __restrict__ rw,
    const void* __restrict__ rb, const int* __restrict__ flag,
    u16* __restrict__ outq, u16* __restrict__ outo,
    u16* __restrict__ out1, u16* __restrict__ out2,
    float* __restrict__ probs)
{
    __shared__ float shm[2048];
    const bool f32 = (*flag != 0);
    if (blockIdx.x < 3072) {
        float (*t)[33] = (float(*)[33])shm;    // 32x33 transpose tile
        int i = blockIdx.x;
        const void* in; u16* out; int K, N, kb, nb;
        if (i < 768)       { in = wqkv; out = outq; K = 512;  N = 1536; kb = (i & 15) * 32; nb = (i >> 4) * 32; }
        else if (i < 1024) { i -= 768;  in = wo; out = outo; K = 512;  N = 512;  kb = (i & 15) * 32; nb = (i >> 4) * 32; }
        else if (i < 2048) { i -= 1024; in = w1; out = out1; K = 512;  N = 2048; kb = (i & 15) * 32; nb = (i >> 4) * 32; }
        else               { i -= 2048; in = w2; out = out2; K = 2048; N = 512;  kb = (i & 63) * 32; nb = (i >> 6) * 32; }
        const int tx = threadIdx.x & 7, ty = threadIdx.x >> 3;
        #pragma unroll
        for (int j = 0; j < 4; ++j)
            t[ty][tx * 4 + j] = ldf(in, (size_t)(kb + ty) * N + nb + tx * 4 + j, f32);
        __syncthreads();
        #pragma unroll
        for (int j = 0; j < 4; ++j)
            out[(size_t)(nb + ty) * K + kb + tx * 4 + j] = f2bf(t[tx * 4 + j][ty]);
        return;
    }
    // router probs
    for (int i = threadIdx.x; i < DMODEL * 4; i += 256) shm[i] = ldf(rw, i, f32);
    __syncthreads();
    const int w = threadIdx.x >> 6, l = threadIdx.x & 63;
    const int t = (blockIdx.x - 3072) * 4 + w;
    double a0 = (double)ldf(rb, 0, f32), a1 = (double)ldf(rb, 1, f32);
    double a2 = (double)ldf(rb, 2, f32), a3 = (double)ldf(rb, 3, f32);
    const size_t xbase = (size_t)t * DMODEL + l * 8;
    #pragma unroll
    for (int j = 0; j < 8; ++j) {
        double xv = (double)ldf(xg, xbase + j, f32);
        int d = l * 8 + j;
        a0 += xv * (double)shm[d * 4 + 0];
        a1 += xv * (double)shm[d * 4 + 1];
        a2 += xv * (double)shm[d * 4 + 2];
        a3 += xv * (double)shm[d * 4 + 3];
    }
    #pragma unroll
    for (int off = 32; off > 0; off >>= 1) {
        a0 += __shfl_xor(a0, off);
        a1 += __shfl_xor(a1, off);
        a2 += __shfl_xor(a2, off);
        a3 += __shfl_xor(a3, off);
    }
    if (l == 0) {
        double mx = fmax(fmax(a0, a1), fmax(a2, a3));
        double e0 = exp(a0 - mx), e1 = exp(a1 - mx), e2 = exp(a2 - mx), e3 = exp(a3 - mx);
        double s = e0 + e1 + e2 + e3;
        float4 p = make_float4((float)(e0 / s), (float)(e1 / s),
                               (float)(e2 / s), (float)(e3 / s));
        *reinterpret_cast<float4*>(probs + (size_t)t * 4) = p;
    }
}

// ---------------------------------------------------------------------------
// Router phase B: per (batch, expert e=3,2,1) bitonic sort of u64 keys
// ((probbits<<32) | (2047-idx)) descending == (prob desc, idx asc).
__global__ __launch_bounds__(1024) void rsort_kernel(
    const float* __restrict__ probs, u16* __restrict__ sortedIdx)
{
    __shared__ u64 sk[NSEQ];   // 16 KB
    const int bid = blockIdx.x;
    const int b = bid / 3, ei = bid % 3, e = 3 - ei;
    const int tid = threadIdx.x;
    for (int n = tid; n < NSEQ; n += 1024) {
        unsigned fb = __float_as_uint(probs[((size_t)b * NSEQ + n) * 4 + e]);
        sk[n] = ((u64)fb << 32) | (unsigned)(2047 - n);
    }
    for (unsigned k = 2; k <= NSEQ; k <<= 1) {
        for (unsigned j = k >> 1; j > 0; j >>= 1) {
            __syncthreads();
            unsigned i = ((tid & ~(j - 1)) << 1) | (tid & (j - 1));
            unsigned ixj = i | j;
            u64 a = sk[i], c = sk[ixj];
            bool up = ((i & k) == 0);
            if ((a < c) == up) { sk[i] = c; sk[ixj] = a; }
        }
    }
    __syncthreads();
    u16* out = sortedIdx + ((size_t)b * 3 + ei) * NSEQ;
    for (int n = tid; n < NSEQ; n += 1024)
        out[n] = (u16)(2047u - (unsigned)(sk[n] & 0xFFFFFFFFu));
}

// ---------------------------------------------------------------------------
// Router phase C: greedy capacity selection per batch (e=3,2,1; leftovers->0),
// emit dtok/rpw/outputs, the expert-sorted permutation perm, and its inverse
// posOf (token -> compacted position).
__global__ __launch_bounds__(1024) void rassign_kernel(
    const float* __restrict__ probs, const u16* __restrict__ sortedIdx,
    const int* __restrict__ flag, int* __restrict__ dtok, float* __restrict__ rpw,
    int* __restrict__ perm, int* __restrict__ posOf, void* __restrict__ outp)
{
    __shared__ int sassigned[NSEQ];   // 8 KB
    __shared__ int wsum[16];
    const int b = blockIdx.x;
    const int tid = threadIdx.x;
    const int lane = tid & 63;
    const bool f32 = (*flag != 0);
    for (int n = tid; n < NSEQ; n += 1024) sassigned[n] = -1;
    __syncthreads();
    const int caps[3] = {256, 256, 512};   // e = 3, 2, 1
    #pragma unroll
    for (int ei = 0; ei < 3; ++ei) {
        const int e = 3 - ei, cap = caps[ei];
        const u16* sl = sortedIdx + ((size_t)b * 3 + ei) * NSEQ;
        int t0 = sl[2 * tid], t1 = sl[2 * tid + 1];
        int f0 = (sassigned[t0] < 0) ? 1 : 0;
        int f1 = (sassigned[t1] < 0) ? 1 : 0;
        int s = f0 + f1;
        #pragma unroll
        for (int off = 1; off < 64; off <<= 1) {
            int v = __shfl_up(s, off);
            if (lane >= off) s += v;
        }
        if (lane == 63) wsum[tid >> 6] = s;
        __syncthreads();
        if (tid < 16) {
            int v = wsum[tid];
            #pragma unroll
            for (int off = 1; off < 16; off <<= 1) {
                int u = __shfl_up(v, off);
                if (tid >= off) v += u;
            }
            wsum[tid] = v;
        }
        __syncthreads();
        int wprev = (tid >> 6) ? wsum[(tid >> 6) - 1] : 0;
        int excl0 = s + wprev - f0 - f1;   // rank of t0 among unassigned
        if (f0 && excl0 < cap) sassigned[t0] = e;
        if (f1 && excl0 + f0 < cap) sassigned[t1] = e;
        __syncthreads();
    }
    // leftovers -> expert 0
    for (int n = tid; n < NSEQ; n += 1024)
        if (sassigned[n] < 0) sassigned[n] = 0;
    __syncthreads();
    // stable perm: for each expert, block-scan rank in ascending token order
    #pragma unroll
    for (int e = 0; e < 4; ++e) {
        const int n0 = 2 * tid, n1 = 2 * tid + 1;
        const int f0 = (sassigned[n0] == e) ? 1 : 0;
        const int f1 = (sassigned[n1] == e) ? 1 : 0;
        int s = f0 + f1;
        #pragma unroll
        for (int off = 1; off < 64; off <<= 1) {
            int v = __shfl_up(s, off);
            if (lane >= off) s += v;
        }
        if (lane == 63) wsum[tid >> 6] = s;
        __syncthreads();
        if (tid < 16) {
            int v = wsum[tid];
            #pragma unroll
            for (int off = 1; off < 16; off <<= 1) {
                int u = __shfl_up(v, off);
                if (tid >= off) v += u;
            }
            wsum[tid] = v;
        }
        __syncthreads();
        int wprev = (tid >> 6) ? wsum[(tid >> 6) - 1] : 0;
        int rank0 = s + wprev - f0 - f1;
        const int offe = (e == 3) ? 0 : (e == 2) ? 256 : (e == 1) ? 512 : 1024;
        if (f0) { perm[b * NSEQ + offe + rank0] = n0;      posOf[b * NSEQ + n0] = offe + rank0; }
        if (f1) { perm[b * NSEQ + offe + rank0 + f0] = n1; posOf[b * NSEQ + n1] = offe + rank0 + f0; }
        __syncthreads();
    }
    const size_t base0 = (size_t)TOK * DMODEL;
    for (int n = tid; n < NSEQ; n += 1024) {
        int e = sassigned[n];
        size_t g = (size_t)b * NSEQ + n;
        dtok[g] = 64 << e;
        float rpv = probs[g * 4 + e];
        rpw[g] = rpv;
        stf(outp, base0 + g, (float)e, f32);
        stf(outp, base0 + TOK + g, rpv, f32);
    }
}

// ---------------------------------------------------------------------------
// LayerNorm in COMPACTED order, ONE WAVE PER ROW (4 rows/block, no barriers).
// Single pass: sum and sum of squares, var = E[x^2] - mu^2.
// INMODE 0: input x (native dtype), gathered via perm. INMODE 1: input zC fp32.
template <int INMODE>
__global__ __launch_bounds__(256) void ln_kernel(
    const void* __restrict__ in, const void* __restrict__ gw, const void* __restrict__ bw,
    const int* __restrict__ flag, const int* __restrict__ perm, u16* __restrict__ out)
{
    const int w = threadIdx.x >> 6, l = threadIdx.x & 63;
    const int row = blockIdx.x * 4 + w;
    const bool f32 = (*flag != 0);
    size_t srow;
    if (INMODE == 0) {
        srow = (size_t)(row & ~(NSEQ - 1)) + perm[row];
    } else {
        srow = (size_t)row;
    }
    const int j0 = l * 8;
    float v[8];
    if (INMODE == 1 || f32) {
        const float4* p = (const float4*)((const float*)in + srow * DMODEL + j0);
        float4 u0 = p[0], u1 = p[1];
        v[0] = u0.x; v[1] = u0.y; v[2] = u0.z; v[3] = u0.w;
        v[4] = u1.x; v[5] = u1.y; v[6] = u1.z; v[7] = u1.w;
    } else {
        const u16* p = (const u16*)in + srow * DMODEL + j0;
        uint4 u = *(const uint4*)p;
        const u16* pu = (const u16*)&u;
        #pragma unroll
        for (int j = 0; j < 8; ++j) v[j] = bf2f(pu[j]);
    }
    float s = 0.f, s2 = 0.f;
    #pragma unroll
    for (int j = 0; j < 8; ++j) { s += v[j]; s2 += v[j] * v[j]; }
    #pragma unroll
    for (int off = 32; off > 0; off >>= 1) {
        s  += __shfl_xor(s, off);
        s2 += __shfl_xor(s2, off);
    }
    const float mu = s * (1.0f / DMODEL);
    const float var = s2 * (1.0f / DMODEL) - mu * mu;
    const float inv = rsqrtf(var + 1e-5f);
    const int dt = dt_of_pos(row & (NSEQ - 1));
    u16 o[8];
    #pragma unroll
    for (int j = 0; j < 8; ++j) {
        const int c = j0 + j;
        float r = (c < dt) ? ((v[j] - mu) * inv * ldf(gw, c, f32) + ldf(bw, c, f32)) : 0.0f;
        o[j] = f2bf(r);
    }
    *(uint4*)(out + (size_t)row * DMODEL + j0) = *(const uint4*)o;
}

// ---------------------------------------------------------------------------
__device__ __forceinline__ float gelu_tanh(float x) {
    float x3 = x * x * x;
    float t = tanhf(0.7978845608028654f * (x + 0.044715f * x3));
    return 0.5f * x * (1.0f + t);
}

// Group-sparse MFMA GEMM over expert-compacted rows. Per-batch groups
// (e3:256 rows dt=512 | e2:256 dt=256 | e1:512 dt=128 | e0:1024 dt=64).
// 128x64 tiles. Double-buffered LDS, one barrier per K-step; staging regs
// transient within an iteration (rounds 7/11 spill lesson).
// MODE 0: hC@dt  x wqkvT -> qkvC, N tiles = 3 slices x dt          (K=dt)
// MODE 1: obC@dt x woT   -> zC = v_masked + x[perm],  N full 512   (K=dt)
// MODE 2: hmC@dt x w1T   -> hidC = gelu(+bias), N tiles = 4dt      (K=dt)
// MODE 3: hidC   x w2T   -> g3 ONLY split-K kc=4 -> fp32 partials in Part;
//          g2/g1/g0 full epilogue in-kernel (K=4dt).
template <int MODE>
__global__ __launch_bounds__(256, 2) void ggemm_kernel(
    const u16* __restrict__ A, const u16* __restrict__ Bt, const void* __restrict__ bias,
    const int* __restrict__ flag, const int* __restrict__ perm, const float* __restrict__ rp,
    const void* __restrict__ resx, const float* __restrict__ resz, const void* __restrict__ alp,
    float* __restrict__ Part,
    void* __restrict__ C, float* __restrict__ Cz, int Ncols, int Kdim)
{
    constexpr int T = (MODE == 0) ? 120 : (MODE == 1) ? 128 : (MODE == 2) ? 160 : 88;
    __shared__ u16 As[2][128][72];   // 36 KB
    __shared__ u16 Bs[2][64][72];    // 18 KB
    const int tid = threadIdx.x;
    const bool f32 = (*flag != 0);
    const int w = tid >> 6, l = tid & 63, ln = l & 15, lg = l >> 4;
    const int wr = w >> 1, wc = w & 1;

    // decode (batch, group g, mtile, ntile, kchunk)
    const int batch = blockIdx.x / T;
    int r = blockIdx.x % T;
    int g = 3, mt = 0, nt = 0, kc = 0;
    #pragma unroll
    for (int gg = 3; gg >= 0; --gg) {
        const int NTg = (MODE == 0) ? 3 * (1 << gg) : (MODE == 1) ? 8
                       : (MODE == 2) ? (4 << gg) : (1 << gg);
        const int MTg = (gg == 0) ? 8 : (gg == 1) ? 4 : 2;
        const int KCg = (MODE == 3 && gg == 3) ? 4 : 1;
        const int cnt = MTg * NTg * KCg;
        if (r >= 0 && r < cnt) {
            g = gg; mt = r / (NTg * KCg);
            int rem = r % (NTg * KCg);
            nt = rem / KCg; kc = rem % KCg;
        }
        r -= cnt;
    }
    const int dtg = 64 << g;
    const int offg = (g == 3) ? 0 : (g == 2) ? 256 : (g == 1) ? 512 : 1024;
    const int rowbase = batch * NSEQ + offg + mt * 128;
    int c0;
    if (MODE == 0) {
        const int per = 1 << g;                 // dt/64
        c0 = (nt / per) * DMODEL + (nt % per) * 64;
    } else {
        c0 = nt * 64;
    }
    const int Keff = (MODE == 3) ? 4 * dtg : dtg;
    const int KCg = (MODE == 3 && g == 3) ? 4 : 1;
    const int Klen = Keff / KCg;
    const int kbeg = kc * Klen;

    f32x4 acc[4][2];
    #pragma unroll
    for (int mi = 0; mi < 4; ++mi) {
        acc[mi][0] = f32x4{0.f, 0.f, 0.f, 0.f};
        acc[mi][1] = f32x4{0.f, 0.f, 0.f, 0.f};
    }

    const int sr = tid >> 1, sc0 = (tid & 1) * 32;   // A staging
    const int br = tid >> 2, bc0 = (tid & 3) * 16;   // B staging
    auto stage = [&](int k0, int buf) {
        const u16* srcA = A + (size_t)(rowbase + sr) * Kdim + k0 + sc0;
        uint4 a0 = *(const uint4*)(srcA);
        uint4 a1 = *(const uint4*)(srcA + 8);
        uint4 a2 = *(const uint4*)(srcA + 16);
        uint4 a3 = *(const uint4*)(srcA + 24);
        *(uint4*)&As[buf][sr][sc0]      = a0;
        *(uint4*)&As[buf][sr][sc0 + 8]  = a1;
        *(uint4*)&As[buf][sr][sc0 + 16] = a2;
        *(uint4*)&As[buf][sr][sc0 + 24] = a3;
        const u16* srcB = Bt + (size_t)(c0 + br) * Kdim + k0 + bc0;
        uint4 b0 = *(const uint4*)(srcB);
        uint4 b1 = *(const uint4*)(srcB + 8);
        *(uint4*)&Bs[buf][br][bc0]     = b0;
        *(uint4*)&Bs[buf][br][bc0 + 8] = b1;
    };

    stage(kbeg, 0);
    int cur = 0;
    for (int k0 = kbeg; k0 < kbeg + Klen; k0 += 64) {
        __syncthreads();
        if (k0 + 64 < kbeg + Klen) stage(k0 + 64, cur ^ 1);
        bf16x8 fb[2][2];
        #pragma unroll
        for (int ci = 0; ci < 2; ++ci)
            #pragma unroll
            for (int ks = 0; ks < 2; ++ks)
                fb[ci][ks] = *reinterpret_cast<const bf16x8*>(
                    &Bs[cur][wc * 32 + ci * 16 + ln][ks * 32 + lg * 8]);
        __builtin_amdgcn_s_setprio(1);
        #pragma unroll
        for (int mi = 0; mi < 4; ++mi) {
            bf16x8 fa0 = *reinterpret_cast<const bf16x8*>(
                &As[cur][wr * 64 + mi * 16 + ln][lg * 8]);
            bf16x8 fa1 = *reinterpret_cast<const bf16x8*>(
                &As[cur][wr * 64 + mi * 16 + ln][32 + lg * 8]);
            #pragma unroll
            for (int ci = 0; ci < 2; ++ci) {
                acc[mi][ci] = __builtin_amdgcn_mfma_f32_16x16x32_bf16(fa0, fb[ci][0], acc[mi][ci], 0, 0, 0);
                acc[mi][ci] = __builtin_amdgcn_mfma_f32_16x16x32_bf16(fa1, fb[ci][1], acc[mi][ci], 0, 0, 0);
            }
        }
        __builtin_amdgcn_s_setprio(0);
        cur ^= 1;
    }

    // MODE 3 g3: raw fp32 partial (bias/gate/z applied in greduce)
    if (MODE == 3 && KCg > 1) {
        const int slot = (mt * 8 + nt) * 4 + kc;     // 0..63
        float* pp = Part + ((size_t)(batch * 64 + slot) * 128) * 64;
        #pragma unroll
        for (int mi = 0; mi < 4; ++mi)
            #pragma unroll
            for (int rr = 0; rr < 4; ++rr) {
                const int lrow = wr * 64 + mi * 16 + 4 * lg + rr;
                #pragma unroll
                for (int ci = 0; ci < 2; ++ci)
                    pp[lrow * 64 + wc * 32 + ci * 16 + ln] = acc[mi][ci][rr];
            }
        return;
    }

    const float alphav = (MODE == 3) ? ldf(alp, 0, f32) : 0.0f;
    #pragma unroll
    for (int mi = 0; mi < 4; ++mi) {
        #pragma unroll
        for (int rr = 0; rr < 4; ++rr) {
            const int row = rowbase + wr * 64 + mi * 16 + 4 * lg + rr;
            #pragma unroll
            for (int ci = 0; ci < 2; ++ci) {
                const int c = c0 + wc * 32 + ci * 16 + ln;
                float v = acc[mi][ci][rr];
                if (MODE == 0) {
                    ((u16*)C)[(size_t)row * Ncols + c] = f2bf(v);
                } else if (MODE == 1) {
                    v += ldf(bias, c, f32);
                    if (c >= dtg) v = 0.0f;
                    const size_t xrow = (size_t)(row & ~(NSEQ - 1)) + perm[row];
                    v += ldf(resx, xrow * DMODEL + c, f32);
                    Cz[(size_t)row * DMODEL + c] = v;
                } else if (MODE == 2) {
                    v += ldf(bias, c, f32);
                    ((u16*)C)[(size_t)row * Ncols + c] = f2bf(gelu_tanh(v));
                } else {
                    v += ldf(bias, c, f32);
                    const size_t orow = (size_t)(row & ~(NSEQ - 1)) + perm[row];
                    const float gate = 1.0f + alphav * rp[orow];
                    float outv = resz[(size_t)row * DMODEL + c] + gate * v;
                    stf(C, orow * DMODEL + c, outv, f32);
                }
            }
        }
    }
}

// ---------------------------------------------------------------------------
// Combined split-K reduce (g3 rows, pos<256) + fill pass (pos>=256):
// one block per (batch, compacted pos).
__global__ __launch_bounds__(256) void gredfill_kernel(
    const float* __restrict__ Part, const void* __restrict__ bias,
    const float* __restrict__ rp, const int* __restrict__ perm,
    const int* __restrict__ flag, const float* __restrict__ zC,
    const void* __restrict__ alp, void* __restrict__ outp)
{
    const bool f32 = (*flag != 0);
    const int b = blockIdx.x >> 11;         // / 2048
    const int pos = blockIdx.x & 2047;
    const int row = b * NSEQ + pos;
    const size_t orow = (size_t)b * NSEQ + perm[row];
    if (pos < 256) {
        const int mt = pos >> 7, rowIn = pos & 127;
        const float alphav = ldf(alp, 0, f32);
        const float gate = 1.0f + alphav * rp[orow];
        for (int c = threadIdx.x; c < DMODEL; c += 256) {
            const int nt = c >> 6, col = c & 63;
            const int slot0 = (mt * 8 + nt) * 4;
            float v = 0.0f;
            #pragma unroll
            for (int i = 0; i < 4; ++i)
                v += Part[((size_t)(b * 64 + slot0 + i) * 128 + rowIn) * 64 + col];
            v += ldf(bias, c, f32);
            float outv = zC[(size_t)row * DMODEL + c] + gate * v;
            stf(outp, orow * DMODEL + c, outv, f32);
        }
    } else {
        const int dt = dt_of_pos(pos);
        for (int c = dt + threadIdx.x; c < DMODEL; c += 256)
            stf(outp, orow * DMODEL + c, zC[(size_t)row * DMODEL + c], f32);
    }
}

// ---------------------------------------------------------------------------
// V transpose: qkvC (compacted) V-slice -> VT[(b*8+h)*64 + d][NSEQ pos].
__global__ __launch_bounds__(256) void vtrans_kernel(
    const u16* __restrict__ qkvC, u16* __restrict__ VT)
{
    __shared__ u16 tl[64][72];
    const int bh = blockIdx.y, b = bh >> 3, hh = bh & 7;
    const int k0 = blockIdx.x * 64;
    const int tid = threadIdx.x;
    #pragma unroll
    for (int p = 0; p < 2; ++p) {
        int idx = p * 256 + tid;
        int row = idx >> 3, c8 = (idx & 7) * 8;
        uint4 v = *(const uint4*)(qkvC + ((size_t)b * NSEQ + k0 + row) * 1536
                                  + 1024 + hh * 64 + c8);
        const u16* pv = (const u16*)&v;
        #pragma unroll
        for (int j = 0; j < 8; ++j) tl[c8 + j][row] = pv[j];
    }
    __syncthreads();
    #pragma unroll
    for (int p = 0; p < 2; ++p) {
        int idx = p * 256 + tid;
        int d = idx >> 3, k8 = (idx & 7) * 8;
        uint4 o = *(const uint4*)&tl[d][k8];
        *(uint4*)(VT + ((size_t)bh * 64 + d) * NSEQ + k0 + k8) = o;
    }
}

// ---------------------------------------------------------------------------
// Split-K flash attention, phase 1. Round-15 split (512-key chunks): per batch
// 192 slots — h0: qc*4+kc | h1: 128+qc*2+kc | h2: 160+qc | h3: 168+qc |
// h4-7: 176+(h-4)*4+qc. Heads h2..h7 (nkc==1) normalize in-kernel and write
// obC directly; h0/h1 emit partials. Double-buffered K/V LDS, one barrier/tile.
__global__ __launch_bounds__(256, 2) void attnp_kernel(
    const u16* __restrict__ qkvC, const u16* __restrict__ VT,
    u16* __restrict__ Opart, float* __restrict__ ml, u16* __restrict__ ob)
{
    __shared__ u16 Ks[2][64 * 72];   // 18 KB
    __shared__ u16 Vs[2][64 * 72];   // 18 KB (transposed: Vs[d][key])
    __shared__ u16 Ps[4 * 16 * 72];  //  9 KB

    const int bid = blockIdx.x;
    const int b = bid / 192;
    const int rr = bid % 192;
    int hh, qc, kc, C;
    if (rr < 128)      { hh = 0; qc = rr >> 2;        kc = rr & 3; C = 2048; }
    else if (rr < 160) { int t = rr - 128; hh = 1; qc = t >> 1; kc = t & 1; C = 1024; }
    else if (rr < 168) { hh = 2; qc = rr - 160; kc = 0; C = 512; }
    else if (rr < 176) { hh = 3; qc = rr - 168; kc = 0; C = 512; }
    else { int t = rr - 176; hh = 4 + (t >> 2); qc = t & 3; kc = 0; C = 256; }
    const int k_beg = kc * 512;
    const int k_end = (k_beg + 512 < C) ? (k_beg + 512) : C;

    const int tid = threadIdx.x;
    const int w = tid >> 6, l = tid & 63;
    const int ln = l & 15, lg = l >> 4;

    const size_t bbase = (size_t)b * NSEQ;
    const int q0 = qc * 64 + w * 16;

    bf16x8 qa[2];
    {
        const u16* qrow = qkvC + (bbase + q0 + ln) * 1536 + hh * 64;
        #pragma unroll
        for (int s = 0; s < 2; ++s) {
            bf16x8 t = *reinterpret_cast<const bf16x8*>(qrow + 8 * lg + 32 * s);
            #pragma unroll
            for (int j = 0; j < 8; ++j) t[j] = (__bf16)((float)t[j] * 0.125f);
            qa[s] = t;
        }
    }

    const int srow = tid >> 3, sc8 = (tid & 7) * 8;
    const u16* kbase = qkvC + (bbase + srow) * 1536 + 512 + hh * 64 + sc8;
    const size_t vrowbase = (size_t)(b * 8 + hh) * 64 + srow;
    auto stagea = [&](int t0, int buf) {
        #pragma unroll
        for (int p = 0; p < 2; ++p) {
            int roff = p * 32;
            uint4 kv = *(const uint4*)(kbase + (size_t)(t0 + roff) * 1536);
            uint4 vv = *(const uint4*)(VT + (vrowbase + roff) * NSEQ + t0 + sc8);
            *(uint4*)&Ks[buf][(srow + roff) * 72 + sc8] = kv;
            *(uint4*)&Vs[buf][(srow + roff) * 72 + sc8] = vv;
        }
    };

    f32x4 oacc[4];
    #pragma unroll
    for (int d0 = 0; d0 < 4; ++d0) oacc[d0] = f32x4{0.f, 0.f, 0.f, 0.f};
    float mold[4] = {-INFINITY, -INFINITY, -INFINITY, -INFINITY};
    float lsum[4] = {0.f, 0.f, 0.f, 0.f};
    u16* Pw = Ps + w * 16 * 72;

    stagea(k_beg, 0);
    int cur = 0;
    for (int t0 = k_beg; t0 < k_end; t0 += 64) {
        __syncthreads();
        if (t0 + 64 < k_end) stagea(t0 + 64, cur ^ 1);

        f32x4 sa[4];
        #pragma unroll
        for (int kb = 0; kb < 4; ++kb) sa[kb] = f32x4{0.f, 0.f, 0.f, 0.f};
        __builtin_amdgcn_s_setprio(1);
        #pragma unroll
        for (int kb = 0; kb < 4; ++kb) {
            #pragma unroll
            for (int s = 0; s < 2; ++s) {
                bf16x8 kf = *reinterpret_cast<const bf16x8*>(
                    &Ks[cur][(kb * 16 + ln) * 72 + 8 * lg + 32 * s]);
                sa[kb] = __builtin_amdgcn_mfma_f32_16x16x32_bf16(qa[s], kf, sa[kb], 0, 0, 0);
            }
        }
        __builtin_amdgcn_s_setprio(0);

        float nm[4], sc[4];
        #pragma unroll
        for (int r = 0; r < 4; ++r) {
            float mx = fmaxf(fmaxf(sa[0][r], sa[1][r]), fmaxf(sa[2][r], sa[3][r]));
            mx = fmaxf(mx, __shfl_xor(mx, 1));
            mx = fmaxf(mx, __shfl_xor(mx, 2));
            mx = fmaxf(mx, __shfl_xor(mx, 4));
            mx = fmaxf(mx, __shfl_xor(mx, 8));
            nm[r] = fmaxf(mold[r], mx);
            sc[r] = __expf(mold[r] - nm[r]);
            mold[r] = nm[r];
        }
        float psum[4] = {0.f, 0.f, 0.f, 0.f};
        #pragma unroll
        for (int kb = 0; kb < 4; ++kb) {
            #pragma unroll
            for (int r = 0; r < 4; ++r) {
                float p = __expf(sa[kb][r] - nm[r]);
                psum[r] += p;
                Pw[(4 * lg + r) * 72 + kb * 16 + ln] = f2bf(p);
            }
        }
        #pragma unroll
        for (int r = 0; r < 4; ++r) {
            float s = psum[r];
            s += __shfl_xor(s, 1);
            s += __shfl_xor(s, 2);
            s += __shfl_xor(s, 4);
            s += __shfl_xor(s, 8);
            lsum[r] = lsum[r] * sc[r] + s;
            #pragma unroll
            for (int d0 = 0; d0 < 4; ++d0) oacc[d0][r] *= sc[r];
        }
        asm volatile("s_waitcnt lgkmcnt(0)" ::: "memory");  // P writes visible

        bf16x8 pf[2];
        pf[0] = *reinterpret_cast<const bf16x8*>(&Pw[ln * 72 + 8 * lg]);
        pf[1] = *reinterpret_cast<const bf16x8*>(&Pw[ln * 72 + 8 * lg + 32]);
        __builtin_amdgcn_s_setprio(1);
        #pragma unroll
        for (int d0 = 0; d0 < 4; ++d0) {
            #pragma unroll
            for (int s = 0; s < 2; ++s) {
                bf16x8 vf = *reinterpret_cast<const bf16x8*>(
                    &Vs[cur][(d0 * 16 + ln) * 72 + 8 * lg + 32 * s]);
                oacc[d0] = __builtin_amdgcn_mfma_f32_16x16x32_bf16(pf[s], vf, oacc[d0], 0, 0, 0);
            }
        }
        __builtin_amdgcn_s_setprio(0);
        cur ^= 1;
    }

    if (hh >= 2) {
        // single-chunk heads: normalize + analytic null-key term, write obC
        #pragma unroll
        for (int r = 0; r < 4; ++r) {
            float mf = mold[r];
            float M = fmaxf(mf, 0.0f);           // C < NSEQ always here
            float ec = __expf(mf - M);
            float L = lsum[r] * ec + (float)(NSEQ - C) * __expf(-M);
            float rs = ec / L;
            u16* obp = ob + (bbase + q0 + 4 * lg + r) * DMODEL + hh * 64;
            #pragma unroll
            for (int d0 = 0; d0 < 4; ++d0)
                obp[d0 * 16 + ln] = f2bf(oacc[d0][r] * rs);
        }
        return;
    }

    // h0/h1: write unnormalized partial (row includes wave offset w*16)
    u16* op = Opart + (size_t)bid * 64 * 64;
    #pragma unroll
    for (int r = 0; r < 4; ++r) {
        const int row = w * 16 + 4 * lg + r;
        #pragma unroll
        for (int d0 = 0; d0 < 4; ++d0)
            op[row * 64 + d0 * 16 + ln] = f2bf(oacc[d0][r]);
        if (ln == 0) {
            ml[(size_t)bid * 128 + row] = mold[r];
            ml[(size_t)bid * 128 + 64 + row] = lsum[r];
        }
    }
}

// ---------------------------------------------------------------------------
// Split-K merge for h0/h1 only (h2-7 written directly by attnp).
__global__ __launch_bounds__(256) void attnm_kernel(
    const u16* __restrict__ Opart, const float* __restrict__ ml,
    u16* __restrict__ ob)
{
    const int bid = blockIdx.x;
    const int b = bid / 48;
    const int rr = bid % 48;
    int hh, qc, C, nkc, slot0;
    if (rr < 32) { hh = 0; qc = rr;      C = 2048; nkc = 4; slot0 = b * 192 + qc * 4; }
    else         { hh = 1; qc = rr - 32; C = 1024; nkc = 2; slot0 = b * 192 + 128 + qc * 2; }

    const int tid = threadIdx.x;
    const int r = tid >> 2, cg = (tid & 3) * 16;

    float m[4], li[4];
    float M = -INFINITY;
    for (int i = 0; i < nkc; ++i) {
        m[i]  = ml[(size_t)(slot0 + i) * 128 + r];
        li[i] = ml[(size_t)(slot0 + i) * 128 + 64 + r];
        M = fmaxf(M, m[i]);
    }
    if (C < NSEQ) M = fmaxf(M, 0.0f);
    float L = (C < NSEQ) ? (float)(NSEQ - C) * __expf(-M) : 0.0f;
    float wgt[4];
    for (int i = 0; i < nkc; ++i) {
        wgt[i] = __expf(m[i] - M);
        L += li[i] * wgt[i];
    }
    const float inv = 1.0f / L;

    float o[16];
    #pragma unroll
    for (int j = 0; j < 16; ++j) o[j] = 0.0f;
    for (int i = 0; i < nkc; ++i) {
        const u16* p = Opart + ((size_t)(slot0 + i) * 64 + r) * 64 + cg;
        uint4 v0 = *(const uint4*)(p);
        uint4 v1 = *(const uint4*)(p + 8);
        const u16* pv0 = (const u16*)&v0;
        const u16* pv1 = (const u16*)&v1;
        #pragma unroll
        for (int j = 0; j < 8; ++j) {
            o[j]     += wgt[i] * bf2f(pv0[j]);
            o[8 + j] += wgt[i] * bf2f(pv1[j]);
        }
    }
    u16* obp = ob + ((size_t)b * NSEQ + qc * 64 + r) * DMODEL + hh * 64 + cg;
    #pragma unroll
    for (int j = 0; j < 16; ++j) obp[j] = f2bf(o[j] * inv);
}

// ---------------------------------------------------------------------------
extern "C" void kernel_launch(void* const* d_in, const int* in_sizes, int n_in,
                              void* d_out, int out_size, void* d_ws, size_t ws_size,
                              hipStream_t stream)
{
    (void)in_sizes; (void)n_in; (void)out_size; (void)ws_size;
    const void* x    = d_in[0];
    const void* r_w  = d_in[1];
    const void* r_b  = d_in[2];
    const void* g1   = d_in[3];
    const void* b1   = d_in[4];
    const void* g2   = d_in[5];
    const void* b2   = d_in[6];
    const void* wqkv = d_in[7];
    const void* wo   = d_in[8];
    const void* bo   = d_in[9];
    const void* w1   = d_in[10];
    const void* b1f  = d_in[11];
    const void* w2   = d_in[12];
    const void* b2f  = d_in[13];
    const void* alp  = d_in[14];

    // Workspace overlay (~63.3 MB), all intermediates in COMPACTED order:
    //   [0,8M)    hC / hmC (bf16); dead after ggemm<2> -> Part (fp32, 8MB)
    //   [8M,32M)  qkvC (bf16); later zC (fp32) @ [8M,24M)
    //   [24M,56M) hidC (bf16) — LIVE during ggemm<3>
    //   [32M,40M) obC (bf16)
    //   [40M,48M) Opart (768 slots x 8KB; only h0/h1 slots written)
    //   [48M,56M) VT (live during attnp)
    //   [56M,62M) bf16 transposed weights
    //   [62M,63M) ml (768 x 128 fp32)
    //   [63M,..)  meta
    const size_t MB = 1024 * 1024;
    char* ws = (char*)d_ws;
    u16*   hC     = (u16*)  (ws);
    u16*   hmC    = (u16*)  (ws);
    float* Part   = (float*)(ws);                           // ggemm<3> partials (8MB)
    u16*   qkvC   = (u16*)  (ws + 8 * MB);
    float* zC     = (float*)(ws + 8 * MB);
    u16*   hidC   = (u16*)  (ws + 24 * MB);
    u16*   obC    = (u16*)  (ws + 32 * MB);
    u16*   Opart  = (u16*)  (ws + 40 * MB);                 // 768 slots x 8KB
    u16*   VT     = (u16*)  (ws + 48 * MB);                 // [B*8*64][2048]
    u16*   wqkvT  = (u16*)  (ws + 56 * MB);                 // [1536][512]
    u16*   woT    = (u16*)  (ws + 56 * MB + 1572864);       // [512][512]
    u16*   w1T    = (u16*)  (ws + 56 * MB + 2097152);       // [2048][512]
    u16*   w2T    = (u16*)  (ws + 56 * MB + 4194304);       // [512][2048]
    float* mlbuf  = (float*)(ws + 62 * MB);                 // 768 x 128 fp32
    int*   flag   = (int*)  (ws + 63 * MB);
    int*   dtok   = (int*)  (ws + 63 * MB + 1024);
    float* rpw    = (float*)(ws + 63 * MB + 1024 + 32768);
    float* probs  = (float*)(ws + 63 * MB + 1024 + 65536);          // [TOK][4]
    u16*   sorted = (u16*)  (ws + 63 * MB + 1024 + 65536 + 131072); // [B][3][2048]
    int*   perm   = (int*)  (ws + 63 * MB + 1024 + 65536 + 131072 + 49152);
    int*   posOf  = (int*)  (ws + 63 * MB + 1024 + 65536 + 131072 + 49152 + 32768);

    detect_kernel<<<1, 256, 0, stream>>>((const u16*)x, flag);
    prep_kernel<<<5120, 256, 0, stream>>>(wqkv, wo, w1, w2, x, r_w, r_b, flag,
                                          wqkvT, woT, w1T, w2T, probs);
    rsort_kernel<<<BATCH * 3, 1024, 0, stream>>>(probs, sorted);
    rassign_kernel<<<BATCH, 1024, 0, stream>>>(probs, sorted, flag, dtok, rpw,
                                               perm, posOf, d_out);
    ln_kernel<0><<<TOK / 4, 256, 0, stream>>>(x, g1, b1, flag, perm, hC);
    ggemm_kernel<0><<<BATCH * 120, 256, 0, stream>>>(
        hC, wqkvT, nullptr, flag, perm, nullptr, nullptr, nullptr, nullptr, nullptr,
        qkvC, nullptr, 1536, 512);
    vtrans_kernel<<<dim3(NSEQ / 64, BATCH * 8), 256, 0, stream>>>(qkvC, VT);
    attnp_kernel<<<BATCH * 192, 256, 0, stream>>>(qkvC, VT, Opart, mlbuf, obC);
    attnm_kernel<<<BATCH * 48, 256, 0, stream>>>(Opart, mlbuf, obC);
    ggemm_kernel<1><<<BATCH * 128, 256, 0, stream>>>(
        obC, woT, bo, flag, perm, nullptr, x, nullptr, nullptr, nullptr,
        nullptr, zC, 512, 512);
    ln_kernel<1><<<TOK / 4, 256, 0, stream>>>(zC, g2, b2, flag, perm, hmC);
    ggemm_kernel<2><<<BATCH * 160, 256, 0, stream>>>(
        hmC, w1T, b1f, flag, perm, nullptr, nullptr, nullptr, nullptr, nullptr,
        hidC, nullptr, 2048, 512);
    ggemm_kernel<3><<<BATCH * 88, 256, 0, stream>>>(
        hidC, w2T, b2f, flag, perm, rpw, nullptr, zC, alp, Part,
        d_out, nullptr, 512, 2048);
    gredfill_kernel<<<BATCH * 2048, 256, 0, stream>>>(
        Part, b2f, rpw, perm, flag, zC, alp, d_out);
}

// Round 20
// 168.347 us; speedup vs baseline: 1.2418x; 1.2418x over previous
//
#include <hip/hip_runtime.h>

typedef unsigned short u16;
typedef unsigned long long u64;

#define BATCH  4
#define NSEQ   2048
#define DMODEL 512
#define TOK    8192   // BATCH*NSEQ

typedef __attribute__((ext_vector_type(8))) __bf16 bf16x8;
typedef __attribute__((ext_vector_type(4))) float f32x4;

__device__ __forceinline__ float bf2f(u16 u) {
    unsigned int x = ((unsigned int)u) << 16;
    return __uint_as_float(x);
}
__device__ __forceinline__ u16 f2bf(float f) {
    unsigned int x = __float_as_uint(f);
    unsigned int r = (x + 0x7FFFu + ((x >> 16) & 1u)) >> 16;  // RNE
    return (u16)r;
}
// IO is fp32 (confirmed rounds 3-18; harness input npz is immutable fp32)
__device__ __forceinline__ float ldf(const void* p, size_t i, bool) {
    return ((const float*)p)[i];
}
__device__ __forceinline__ void stf(void* p, size_t i, float v, bool) {
    ((float*)p)[i] = v;
}
// nested dim for compacted position p within a batch (groups e3|e2|e1|e0)
__device__ __forceinline__ int dt_of_pos(int p) {
    return (p < 256) ? 512 : (p < 512) ? 256 : (p < 1024) ? 128 : 64;
}

// ---------------------------------------------------------------------------
// Fused weight convert + transpose for all 4 weights: in [K][N] -> bf16 [N][K].
__global__ __launch_bounds__(256) void wconv_all_kernel(
    const void* __restrict__ wqkv, const void* __restrict__ wo,
    const void* __restrict__ w1, const void* __restrict__ w2,
    u16* __restrict__ outq, u16* __restrict__ outo,
    u16* __restrict__ out1, u16* __restrict__ out2)
{
    __shared__ float t[32][33];
    const bool f32 = true;
    int i = blockIdx.x;
    const void* in; u16* out; int K, N, kb, nb;
    if (i < 768)       { in = wqkv; out = outq; K = 512;  N = 1536; kb = (i & 15) * 32; nb = (i >> 4) * 32; }
    else if (i < 1024) { i -= 768;  in = wo; out = outo; K = 512;  N = 512;  kb = (i & 15) * 32; nb = (i >> 4) * 32; }
    else if (i < 2048) { i -= 1024; in = w1; out = out1; K = 512;  N = 2048; kb = (i & 15) * 32; nb = (i >> 4) * 32; }
    else               { i -= 2048; in = w2; out = out2; K = 2048; N = 512;  kb = (i & 63) * 32; nb = (i >> 6) * 32; }
    const int tx = threadIdx.x & 7, ty = threadIdx.x >> 3;
    #pragma unroll
    for (int j = 0; j < 4; ++j)
        t[ty][tx * 4 + j] = ldf(in, (size_t)(kb + ty) * N + nb + tx * 4 + j, f32);
    __syncthreads();
    #pragma unroll
    for (int j = 0; j < 4; ++j)
        out[(size_t)(nb + ty) * K + kb + tx * 4 + j] = f2bf(t[tx * 4 + j][ty]);
}

// ---------------------------------------------------------------------------
// Router phase A: fp64 logits + softmax, one wave per token.
__global__ __launch_bounds__(256) void rprob_kernel(
    const void* __restrict__ xg, const void* __restrict__ rw, const void* __restrict__ rb,
    float* __restrict__ probs)
{
    __shared__ float srw[DMODEL * 4];
    const bool f32 = true;
    for (int i = threadIdx.x; i < DMODEL * 4; i += 256) srw[i] = ldf(rw, i, f32);
    __syncthreads();
    const int w = threadIdx.x >> 6, l = threadIdx.x & 63;
    const int t = blockIdx.x * 4 + w;
    double a0 = (double)ldf(rb, 0, f32), a1 = (double)ldf(rb, 1, f32);
    double a2 = (double)ldf(rb, 2, f32), a3 = (double)ldf(rb, 3, f32);
    const size_t xbase = (size_t)t * DMODEL + l * 8;
    #pragma unroll
    for (int j = 0; j < 8; ++j) {
        double xv = (double)ldf(xg, xbase + j, f32);
        int d = l * 8 + j;
        a0 += xv * (double)srw[d * 4 + 0];
        a1 += xv * (double)srw[d * 4 + 1];
        a2 += xv * (double)srw[d * 4 + 2];
        a3 += xv * (double)srw[d * 4 + 3];
    }
    #pragma unroll
    for (int off = 32; off > 0; off >>= 1) {
        a0 += __shfl_xor(a0, off);
        a1 += __shfl_xor(a1, off);
        a2 += __shfl_xor(a2, off);
        a3 += __shfl_xor(a3, off);
    }
    if (l == 0) {
        double mx = fmax(fmax(a0, a1), fmax(a2, a3));
        double e0 = exp(a0 - mx), e1 = exp(a1 - mx), e2 = exp(a2 - mx), e3 = exp(a3 - mx);
        double s = e0 + e1 + e2 + e3;
        float4 p = make_float4((float)(e0 / s), (float)(e1 / s),
                               (float)(e2 / s), (float)(e3 / s));
        *reinterpret_cast<float4*>(probs + (size_t)t * 4) = p;
    }
}

// ---------------------------------------------------------------------------
// Router phase B: per (batch, expert e=3,2,1) bitonic sort of u64 keys
// ((probbits<<32) | (2047-idx)) descending == (prob desc, idx asc).
__global__ __launch_bounds__(1024) void rsort_kernel(
    const float* __restrict__ probs, u16* __restrict__ sortedIdx)
{
    __shared__ u64 sk[NSEQ];   // 16 KB
    const int bid = blockIdx.x;
    const int b = bid / 3, ei = bid % 3, e = 3 - ei;
    const int tid = threadIdx.x;
    for (int n = tid; n < NSEQ; n += 1024) {
        unsigned fb = __float_as_uint(probs[((size_t)b * NSEQ + n) * 4 + e]);
        sk[n] = ((u64)fb << 32) | (unsigned)(2047 - n);
    }
    for (unsigned k = 2; k <= NSEQ; k <<= 1) {
        for (unsigned j = k >> 1; j > 0; j >>= 1) {
            __syncthreads();
            unsigned i = ((tid & ~(j - 1)) << 1) | (tid & (j - 1));
            unsigned ixj = i | j;
            u64 a = sk[i], c = sk[ixj];
            bool up = ((i & k) == 0);
            if ((a < c) == up) { sk[i] = c; sk[ixj] = a; }
        }
    }
    __syncthreads();
    u16* out = sortedIdx + ((size_t)b * 3 + ei) * NSEQ;
    for (int n = tid; n < NSEQ; n += 1024)
        out[n] = (u16)(2047u - (unsigned)(sk[n] & 0xFFFFFFFFu));
}

// ---------------------------------------------------------------------------
// Router phase C: greedy capacity selection per batch (e=3,2,1; leftovers->0),
// emit dtok/rpw/outputs, the expert-sorted permutation perm, and its inverse
// posOf (token -> compacted position).
__global__ __launch_bounds__(1024) void rassign_kernel(
    const float* __restrict__ probs, const u16* __restrict__ sortedIdx,
    int* __restrict__ dtok, float* __restrict__ rpw,
    int* __restrict__ perm, int* __restrict__ posOf, void* __restrict__ outp)
{
    __shared__ int sassigned[NSEQ];   // 8 KB
    __shared__ int wsum[16];
    const int b = blockIdx.x;
    const int tid = threadIdx.x;
    const int lane = tid & 63;
    const bool f32 = true;
    for (int n = tid; n < NSEQ; n += 1024) sassigned[n] = -1;
    __syncthreads();
    const int caps[3] = {256, 256, 512};   // e = 3, 2, 1
    #pragma unroll
    for (int ei = 0; ei < 3; ++ei) {
        const int e = 3 - ei, cap = caps[ei];
        const u16* sl = sortedIdx + ((size_t)b * 3 + ei) * NSEQ;
        int t0 = sl[2 * tid], t1 = sl[2 * tid + 1];
        int f0 = (sassigned[t0] < 0) ? 1 : 0;
        int f1 = (sassigned[t1] < 0) ? 1 : 0;
        int s = f0 + f1;
        #pragma unroll
        for (int off = 1; off < 64; off <<= 1) {
            int v = __shfl_up(s, off);
            if (lane >= off) s += v;
        }
        if (lane == 63) wsum[tid >> 6] = s;
        __syncthreads();
        if (tid < 16) {
            int v = wsum[tid];
            #pragma unroll
            for (int off = 1; off < 16; off <<= 1) {
                int u = __shfl_up(v, off);
                if (tid >= off) v += u;
            }
            wsum[tid] = v;
        }
        __syncthreads();
        int wprev = (tid >> 6) ? wsum[(tid >> 6) - 1] : 0;
        int excl0 = s + wprev - f0 - f1;   // rank of t0 among unassigned
        if (f0 && excl0 < cap) sassigned[t0] = e;
        if (f1 && excl0 + f0 < cap) sassigned[t1] = e;
        __syncthreads();
    }
    // leftovers -> expert 0
    for (int n = tid; n < NSEQ; n += 1024)
        if (sassigned[n] < 0) sassigned[n] = 0;
    __syncthreads();
    // stable perm: for each expert, block-scan rank in ascending token order
    #pragma unroll
    for (int e = 0; e < 4; ++e) {
        const int n0 = 2 * tid, n1 = 2 * tid + 1;
        const int f0 = (sassigned[n0] == e) ? 1 : 0;
        const int f1 = (sassigned[n1] == e) ? 1 : 0;
        int s = f0 + f1;
        #pragma unroll
        for (int off = 1; off < 64; off <<= 1) {
            int v = __shfl_up(s, off);
            if (lane >= off) s += v;
        }
        if (lane == 63) wsum[tid >> 6] = s;
        __syncthreads();
        if (tid < 16) {
            int v = wsum[tid];
            #pragma unroll
            for (int off = 1; off < 16; off <<= 1) {
                int u = __shfl_up(v, off);
                if (tid >= off) v += u;
            }
            wsum[tid] = v;
        }
        __syncthreads();
        int wprev = (tid >> 6) ? wsum[(tid >> 6) - 1] : 0;
        int rank0 = s + wprev - f0 - f1;
        const int offe = (e == 3) ? 0 : (e == 2) ? 256 : (e == 1) ? 512 : 1024;
        if (f0) { perm[b * NSEQ + offe + rank0] = n0;      posOf[b * NSEQ + n0] = offe + rank0; }
        if (f1) { perm[b * NSEQ + offe + rank0 + f0] = n1; posOf[b * NSEQ + n1] = offe + rank0 + f0; }
        __syncthreads();
    }
    const size_t base0 = (size_t)TOK * DMODEL;
    for (int n = tid; n < NSEQ; n += 1024) {
        int e = sassigned[n];
        size_t g = (size_t)b * NSEQ + n;
        dtok[g] = 64 << e;
        float rpv = probs[g * 4 + e];
        rpw[g] = rpv;
        stf(outp, base0 + g, (float)e, f32);
        stf(outp, base0 + TOK + g, rpv, f32);
    }
}

// ---------------------------------------------------------------------------
// LayerNorm in COMPACTED order. Block row = compacted position.
// INMODE 0: input x (fp32), gathered via perm. INMODE 1: input zC fp32.
template <int INMODE>
__global__ __launch_bounds__(256) void ln_kernel(
    const void* __restrict__ in, const void* __restrict__ gw, const void* __restrict__ bw,
    const int* __restrict__ perm, u16* __restrict__ out)
{
    const int row = blockIdx.x;            // compacted global row
    const int tid = threadIdx.x;
    const bool f32 = true;
    size_t srow;
    if (INMODE == 0) {
        srow = (size_t)(row & ~(NSEQ - 1)) + perm[row];
    } else {
        srow = (size_t)row;
    }
    size_t base = srow * DMODEL + tid * 2;
    float2 t = *(const float2*)((const float*)in + base);
    float x0 = t.x, x1 = t.y;
    float s = x0 + x1;
    #pragma unroll
    for (int d2 = 32; d2 > 0; d2 >>= 1) s += __shfl_down(s, d2);
    __shared__ float red[4];
    if ((tid & 63) == 0) red[tid >> 6] = s;
    __syncthreads();
    s = red[0] + red[1] + red[2] + red[3];
    float mu = s * (1.0f / DMODEL);
    float d0 = x0 - mu, d1 = x1 - mu;
    float q2 = d0 * d0 + d1 * d1;
    #pragma unroll
    for (int d2 = 32; d2 > 0; d2 >>= 1) q2 += __shfl_down(q2, d2);
    __syncthreads();
    if ((tid & 63) == 0) red[tid >> 6] = q2;
    __syncthreads();
    q2 = red[0] + red[1] + red[2] + red[3];
    float inv = rsqrtf(q2 * (1.0f / DMODEL) + 1e-5f);
    const int dt = dt_of_pos(row & (NSEQ - 1));
    int j0 = tid * 2;
    float r0 = (j0 < dt)     ? (d0 * inv * ldf(gw, j0, f32)     + ldf(bw, j0, f32))     : 0.0f;
    float r1 = (j0 + 1 < dt) ? (d1 * inv * ldf(gw, j0 + 1, f32) + ldf(bw, j0 + 1, f32)) : 0.0f;
    u16* op = out + (size_t)row * DMODEL + j0;
    op[0] = f2bf(r0); op[1] = f2bf(r1);
}

// ---------------------------------------------------------------------------
__device__ __forceinline__ float gelu_tanh(float x) {
    float x3 = x * x * x;
    float t = tanhf(0.7978845608028654f * (x + 0.044715f * x3));
    return 0.5f * x * (1.0f + t);
}

// Group-sparse MFMA GEMM over expert-compacted rows. Per-batch groups
// (e3:256 rows dt=512 | e2:256 dt=256 | e1:512 dt=128 | e0:1024 dt=64).
// 128x64 tiles. Double-buffered LDS, one barrier per K-step; staging regs
// transient within an iteration (rounds 7/11 spill lesson).
// MODE 0: hC@dt  x wqkvT -> qkvC, N tiles = 3 slices x dt          (K=dt)
// MODE 1: obC@dt x woT   -> zC = v_masked + x[perm],  N full 512   (K=dt)
// MODE 2: hmC@dt x w1T   -> hidC = gelu(+bias), N tiles = 4dt      (K=dt)
// MODE 3: hidC   x w2T   -> g3 ONLY split-K kc=4 -> fp32 partials in Part;
//          g2/g1/g0 full epilogue in-kernel (K=4dt).
template <int MODE>
__global__ __launch_bounds__(256, 2) void ggemm_kernel(
    const u16* __restrict__ A, const u16* __restrict__ Bt, const void* __restrict__ bias,
    const int* __restrict__ perm, const float* __restrict__ rp,
    const void* __restrict__ resx, const float* __restrict__ resz, const void* __restrict__ alp,
    float* __restrict__ Part,
    void* __restrict__ C, float* __restrict__ Cz, int Ncols, int Kdim)
{
    constexpr int T = (MODE == 0) ? 120 : (MODE == 1) ? 128 : (MODE == 2) ? 160 : 88;
    __shared__ u16 As[2][128][72];   // 36 KB
    __shared__ u16 Bs[2][64][72];    // 18 KB
    const int tid = threadIdx.x;
    const bool f32 = true;
    const int w = tid >> 6, l = tid & 63, ln = l & 15, lg = l >> 4;
    const int wr = w >> 1, wc = w & 1;

    // decode (batch, group g, mtile, ntile, kchunk)
    const int batch = blockIdx.x / T;
    int r = blockIdx.x % T;
    int g = 3, mt = 0, nt = 0, kc = 0;
    #pragma unroll
    for (int gg = 3; gg >= 0; --gg) {
        const int NTg = (MODE == 0) ? 3 * (1 << gg) : (MODE == 1) ? 8
                       : (MODE == 2) ? (4 << gg) : (1 << gg);
        const int MTg = (gg == 0) ? 8 : (gg == 1) ? 4 : 2;
        const int KCg = (MODE == 3 && gg == 3) ? 4 : 1;
        const int cnt = MTg * NTg * KCg;
        if (r >= 0 && r < cnt) {
            g = gg; mt = r / (NTg * KCg);
            int rem = r % (NTg * KCg);
            nt = rem / KCg; kc = rem % KCg;
        }
        r -= cnt;
    }
    const int dtg = 64 << g;
    const int offg = (g == 3) ? 0 : (g == 2) ? 256 : (g == 1) ? 512 : 1024;
    const int rowbase = batch * NSEQ + offg + mt * 128;
    int c0;
    if (MODE == 0) {
        const int per = 1 << g;                 // dt/64
        c0 = (nt / per) * DMODEL + (nt % per) * 64;
    } else {
        c0 = nt * 64;
    }
    const int Keff = (MODE == 3) ? 4 * dtg : dtg;
    const int KCg = (MODE == 3 && g == 3) ? 4 : 1;
    const int Klen = Keff / KCg;
    const int kbeg = kc * Klen;

    f32x4 acc[4][2];
    #pragma unroll
    for (int mi = 0; mi < 4; ++mi) {
        acc[mi][0] = f32x4{0.f, 0.f, 0.f, 0.f};
        acc[mi][1] = f32x4{0.f, 0.f, 0.f, 0.f};
    }

    const int sr = tid >> 1, sc0 = (tid & 1) * 32;   // A staging
    const int br = tid >> 2, bc0 = (tid & 3) * 16;   // B staging
    auto stage = [&](int k0, int buf) {
        const u16* srcA = A + (size_t)(rowbase + sr) * Kdim + k0 + sc0;
        uint4 a0 = *(const uint4*)(srcA);
        uint4 a1 = *(const uint4*)(srcA + 8);
        uint4 a2 = *(const uint4*)(srcA + 16);
        uint4 a3 = *(const uint4*)(srcA + 24);
        *(uint4*)&As[buf][sr][sc0]      = a0;
        *(uint4*)&As[buf][sr][sc0 + 8]  = a1;
        *(uint4*)&As[buf][sr][sc0 + 16] = a2;
        *(uint4*)&As[buf][sr][sc0 + 24] = a3;
        const u16* srcB = Bt + (size_t)(c0 + br) * Kdim + k0 + bc0;
        uint4 b0 = *(const uint4*)(srcB);
        uint4 b1 = *(const uint4*)(srcB + 8);
        *(uint4*)&Bs[buf][br][bc0]     = b0;
        *(uint4*)&Bs[buf][br][bc0 + 8] = b1;
    };

    stage(kbeg, 0);
    int cur = 0;
    for (int k0 = kbeg; k0 < kbeg + Klen; k0 += 64) {
        __syncthreads();
        if (k0 + 64 < kbeg + Klen) stage(k0 + 64, cur ^ 1);
        bf16x8 fb[2][2];
        #pragma unroll
        for (int ci = 0; ci < 2; ++ci)
            #pragma unroll
            for (int ks = 0; ks < 2; ++ks)
                fb[ci][ks] = *reinterpret_cast<const bf16x8*>(
                    &Bs[cur][wc * 32 + ci * 16 + ln][ks * 32 + lg * 8]);
        __builtin_amdgcn_s_setprio(1);
        #pragma unroll
        for (int mi = 0; mi < 4; ++mi) {
            bf16x8 fa0 = *reinterpret_cast<const bf16x8*>(
                &As[cur][wr * 64 + mi * 16 + ln][lg * 8]);
            bf16x8 fa1 = *reinterpret_cast<const bf16x8*>(
                &As[cur][wr * 64 + mi * 16 + ln][32 + lg * 8]);
            #pragma unroll
            for (int ci = 0; ci < 2; ++ci) {
                acc[mi][ci] = __builtin_amdgcn_mfma_f32_16x16x32_bf16(fa0, fb[ci][0], acc[mi][ci], 0, 0, 0);
                acc[mi][ci] = __builtin_amdgcn_mfma_f32_16x16x32_bf16(fa1, fb[ci][1], acc[mi][ci], 0, 0, 0);
            }
        }
        __builtin_amdgcn_s_setprio(0);
        cur ^= 1;
    }

    // MODE 3 g3: raw fp32 partial (bias/gate/z applied in greduce)
    if (MODE == 3 && KCg > 1) {
        const int slot = (mt * 8 + nt) * 4 + kc;     // 0..63
        float* pp = Part + ((size_t)(batch * 64 + slot) * 128) * 64;
        #pragma unroll
        for (int mi = 0; mi < 4; ++mi)
            #pragma unroll
            for (int rr = 0; rr < 4; ++rr) {
                const int lrow = wr * 64 + mi * 16 + 4 * lg + rr;
                #pragma unroll
                for (int ci = 0; ci < 2; ++ci)
                    pp[lrow * 64 + wc * 32 + ci * 16 + ln] = acc[mi][ci][rr];
            }
        return;
    }

    const float alphav = (MODE == 3) ? ldf(alp, 0, f32) : 0.0f;
    #pragma unroll
    for (int mi = 0; mi < 4; ++mi) {
        #pragma unroll
        for (int rr = 0; rr < 4; ++rr) {
            const int row = rowbase + wr * 64 + mi * 16 + 4 * lg + rr;
            #pragma unroll
            for (int ci = 0; ci < 2; ++ci) {
                const int c = c0 + wc * 32 + ci * 16 + ln;
                float v = acc[mi][ci][rr];
                if (MODE == 0) {
                    ((u16*)C)[(size_t)row * Ncols + c] = f2bf(v);
                } else if (MODE == 1) {
                    v += ldf(bias, c, f32);
                    if (c >= dtg) v = 0.0f;
                    const size_t xrow = (size_t)(row & ~(NSEQ - 1)) + perm[row];
                    v += ldf(resx, xrow * DMODEL + c, f32);
                    Cz[(size_t)row * DMODEL + c] = v;
                } else if (MODE == 2) {
                    v += ldf(bias, c, f32);
                    ((u16*)C)[(size_t)row * Ncols + c] = f2bf(gelu_tanh(v));
                } else {
                    v += ldf(bias, c, f32);
                    const size_t orow = (size_t)(row & ~(NSEQ - 1)) + perm[row];
                    const float gate = 1.0f + alphav * rp[orow];
                    float outv = resz[(size_t)row * DMODEL + c] + gate * v;
                    stf(C, orow * DMODEL + c, outv, f32);
                }
            }
        }
    }
}

// ---------------------------------------------------------------------------
// Combined split-K reduce (g3 rows, pos<256) + fill pass (pos>=256):
// one block per (batch, compacted pos).
__global__ __launch_bounds__(256) void gredfill_kernel(
    const float* __restrict__ Part, const void* __restrict__ bias,
    const float* __restrict__ rp, const int* __restrict__ perm,
    const float* __restrict__ zC, const void* __restrict__ alp,
    void* __restrict__ outp)
{
    const bool f32 = true;
    const int b = blockIdx.x >> 11;         // / 2048
    const int pos = blockIdx.x & 2047;
    const int row = b * NSEQ + pos;
    const size_t orow = (size_t)b * NSEQ + perm[row];
    if (pos < 256) {
        const int mt = pos >> 7, rowIn = pos & 127;
        const float alphav = ldf(alp, 0, f32);
        const float gate = 1.0f + alphav * rp[orow];
        for (int c = threadIdx.x; c < DMODEL; c += 256) {
            const int nt = c >> 6, col = c & 63;
            const int slot0 = (mt * 8 + nt) * 4;
            float v = 0.0f;
            #pragma unroll
            for (int i = 0; i < 4; ++i)
                v += Part[((size_t)(b * 64 + slot0 + i) * 128 + rowIn) * 64 + col];
            v += ldf(bias, c, f32);
            float outv = zC[(size_t)row * DMODEL + c] + gate * v;
            stf(outp, orow * DMODEL + c, outv, f32);
        }
    } else {
        const int dt = dt_of_pos(pos);
        for (int c = dt + threadIdx.x; c < DMODEL; c += 256)
            stf(outp, orow * DMODEL + c, zC[(size_t)row * DMODEL + c], f32);
    }
}

// ---------------------------------------------------------------------------
// V transpose: qkvC (compacted) V-slice -> VT[(b*8+h)*64 + d][NSEQ pos].
__global__ __launch_bounds__(256) void vtrans_kernel(
    const u16* __restrict__ qkvC, u16* __restrict__ VT)
{
    __shared__ u16 tl[64][72];
    const int bh = blockIdx.y, b = bh >> 3, hh = bh & 7;
    const int k0 = blockIdx.x * 64;
    const int tid = threadIdx.x;
    #pragma unroll
    for (int p = 0; p < 2; ++p) {
        int idx = p * 256 + tid;
        int row = idx >> 3, c8 = (idx & 7) * 8;
        uint4 v = *(const uint4*)(qkvC + ((size_t)b * NSEQ + k0 + row) * 1536
                                  + 1024 + hh * 64 + c8);
        const u16* pv = (const u16*)&v;
        #pragma unroll
        for (int j = 0; j < 8; ++j) tl[c8 + j][row] = pv[j];
    }
    __syncthreads();
    #pragma unroll
    for (int p = 0; p < 2; ++p) {
        int idx = p * 256 + tid;
        int d = idx >> 3, k8 = (idx & 7) * 8;
        uint4 o = *(const uint4*)&tl[d][k8];
        *(uint4*)(VT + ((size_t)bh * 64 + d) * NSEQ + k0 + k8) = o;
    }
}

// ---------------------------------------------------------------------------
// Split-K flash attention, phase 1. Round-15 split (512-key chunks): per batch
// 192 slots — h0: qc*4+kc | h1: 128+qc*2+kc | h2: 160+qc | h3: 168+qc |
// h4-7: 176+(h-4)*4+qc. Heads h2..h7 (nkc==1) normalize in-kernel and write
// obC directly; h0/h1 emit partials. Double-buffered K/V LDS, one barrier/tile.
__global__ __launch_bounds__(256, 2) void attnp_kernel(
    const u16* __restrict__ qkvC, const u16* __restrict__ VT,
    u16* __restrict__ Opart, float* __restrict__ ml, u16* __restrict__ ob)
{
    __shared__ u16 Ks[2][64 * 72];   // 18 KB
    __shared__ u16 Vs[2][64 * 72];   // 18 KB (transposed: Vs[d][key])
    __shared__ u16 Ps[4 * 16 * 72];  //  9 KB

    const int bid = blockIdx.x;
    const int b = bid / 192;
    const int rr = bid % 192;
    int hh, qc, kc, C;
    if (rr < 128)      { hh = 0; qc = rr >> 2;        kc = rr & 3; C = 2048; }
    else if (rr < 160) { int t = rr - 128; hh = 1; qc = t >> 1; kc = t & 1; C = 1024; }
    else if (rr < 168) { hh = 2; qc = rr - 160; kc = 0; C = 512; }
    else if (rr < 176) { hh = 3; qc = rr - 168; kc = 0; C = 512; }
    else { int t = rr - 176; hh = 4 + (t >> 2); qc = t & 3; kc = 0; C = 256; }
    const int k_beg = kc * 512;
    const int k_end = (k_beg + 512 < C) ? (k_beg + 512) : C;

    const int tid = threadIdx.x;
    const int w = tid >> 6, l = tid & 63;
    const int ln = l & 15, lg = l >> 4;

    const size_t bbase = (size_t)b * NSEQ;
    const int q0 = qc * 64 + w * 16;

    bf16x8 qa[2];
    {
        const u16* qrow = qkvC + (bbase + q0 + ln) * 1536 + hh * 64;
        #pragma unroll
        for (int s = 0; s < 2; ++s) {
            bf16x8 t = *reinterpret_cast<const bf16x8*>(qrow + 8 * lg + 32 * s);
            #pragma unroll
            for (int j = 0; j < 8; ++j) t[j] = (__bf16)((float)t[j] * 0.125f);
            qa[s] = t;
        }
    }

    const int srow = tid >> 3, sc8 = (tid & 7) * 8;
    const u16* kbase = qkvC + (bbase + srow) * 1536 + 512 + hh * 64 + sc8;
    const size_t vrowbase = (size_t)(b * 8 + hh) * 64 + srow;
    auto stagea = [&](int t0, int buf) {
        #pragma unroll
        for (int p = 0; p < 2; ++p) {
            int roff = p * 32;
            uint4 kv = *(const uint4*)(kbase + (size_t)(t0 + roff) * 1536);
            uint4 vv = *(const uint4*)(VT + (vrowbase + roff) * NSEQ + t0 + sc8);
            *(uint4*)&Ks[buf][(srow + roff) * 72 + sc8] = kv;
            *(uint4*)&Vs[buf][(srow + roff) * 72 + sc8] = vv;
        }
    };

    f32x4 oacc[4];
    #pragma unroll
    for (int d0 = 0; d0 < 4; ++d0) oacc[d0] = f32x4{0.f, 0.f, 0.f, 0.f};
    float mold[4] = {-INFINITY, -INFINITY, -INFINITY, -INFINITY};
    float lsum[4] = {0.f, 0.f, 0.f, 0.f};
    u16* Pw = Ps + w * 16 * 72;

    stagea(k_beg, 0);
    int cur = 0;
    for (int t0 = k_beg; t0 < k_end; t0 += 64) {
        __syncthreads();
        if (t0 + 64 < k_end) stagea(t0 + 64, cur ^ 1);

        f32x4 sa[4];
        #pragma unroll
        for (int kb = 0; kb < 4; ++kb) sa[kb] = f32x4{0.f, 0.f, 0.f, 0.f};
        __builtin_amdgcn_s_setprio(1);
        #pragma unroll
        for (int kb = 0; kb < 4; ++kb) {
            #pragma unroll
            for (int s = 0; s < 2; ++s) {
                bf16x8 kf = *reinterpret_cast<const bf16x8*>(
                    &Ks[cur][(kb * 16 + ln) * 72 + 8 * lg + 32 * s]);
                sa[kb] = __builtin_amdgcn_mfma_f32_16x16x32_bf16(qa[s], kf, sa[kb], 0, 0, 0);
            }
        }
        __builtin_amdgcn_s_setprio(0);

        float nm[4], sc[4];
        #pragma unroll
        for (int r = 0; r < 4; ++r) {
            float mx = fmaxf(fmaxf(sa[0][r], sa[1][r]), fmaxf(sa[2][r], sa[3][r]));
            mx = fmaxf(mx, __shfl_xor(mx, 1));
            mx = fmaxf(mx, __shfl_xor(mx, 2));
            mx = fmaxf(mx, __shfl_xor(mx, 4));
            mx = fmaxf(mx, __shfl_xor(mx, 8));
            nm[r] = fmaxf(mold[r], mx);
            sc[r] = __expf(mold[r] - nm[r]);
            mold[r] = nm[r];
        }
        float psum[4] = {0.f, 0.f, 0.f, 0.f};
        #pragma unroll
        for (int kb = 0; kb < 4; ++kb) {
            #pragma unroll
            for (int r = 0; r < 4; ++r) {
                float p = __expf(sa[kb][r] - nm[r]);
                psum[r] += p;
                Pw[(4 * lg + r) * 72 + kb * 16 + ln] = f2bf(p);
            }
        }
        #pragma unroll
        for (int r = 0; r < 4; ++r) {
            float s = psum[r];
            s += __shfl_xor(s, 1);
            s += __shfl_xor(s, 2);
            s += __shfl_xor(s, 4);
            s += __shfl_xor(s, 8);
            lsum[r] = lsum[r] * sc[r] + s;
            #pragma unroll
            for (int d0 = 0; d0 < 4; ++d0) oacc[d0][r] *= sc[r];
        }
        asm volatile("s_waitcnt lgkmcnt(0)" ::: "memory");  // P writes visible

        bf16x8 pf[2];
        pf[0] = *reinterpret_cast<const bf16x8*>(&Pw[ln * 72 + 8 * lg]);
        pf[1] = *reinterpret_cast<const bf16x8*>(&Pw[ln * 72 + 8 * lg + 32]);
        __builtin_amdgcn_s_setprio(1);
        #pragma unroll
        for (int d0 = 0; d0 < 4; ++d0) {
            #pragma unroll
            for (int s = 0; s < 2; ++s) {
                bf16x8 vf = *reinterpret_cast<const bf16x8*>(
                    &Vs[cur][(d0 * 16 + ln) * 72 + 8 * lg + 32 * s]);
                oacc[d0] = __builtin_amdgcn_mfma_f32_16x16x32_bf16(pf[s], vf, oacc[d0], 0, 0, 0);
            }
        }
        __builtin_amdgcn_s_setprio(0);
        cur ^= 1;
    }

    if (hh >= 2) {
        // single-chunk heads: normalize + analytic null-key term, write obC
        #pragma unroll
        for (int r = 0; r < 4; ++r) {
            float mf = mold[r];
            float M = fmaxf(mf, 0.0f);           // C < NSEQ always here
            float ec = __expf(mf - M);
            float L = lsum[r] * ec + (float)(NSEQ - C) * __expf(-M);
            float rs = ec / L;
            u16* obp = ob + (bbase + q0 + 4 * lg + r) * DMODEL + hh * 64;
            #pragma unroll
            for (int d0 = 0; d0 < 4; ++d0)
                obp[d0 * 16 + ln] = f2bf(oacc[d0][r] * rs);
        }
        return;
    }

    // h0/h1: write unnormalized partial (row includes wave offset w*16)
    u16* op = Opart + (size_t)bid * 64 * 64;
    #pragma unroll
    for (int r = 0; r < 4; ++r) {
        const int row = w * 16 + 4 * lg + r;
        #pragma unroll
        for (int d0 = 0; d0 < 4; ++d0)
            op[row * 64 + d0 * 16 + ln] = f2bf(oacc[d0][r]);
        if (ln == 0) {
            ml[(size_t)bid * 128 + row] = mold[r];
            ml[(size_t)bid * 128 + 64 + row] = lsum[r];
        }
    }
}

// ---------------------------------------------------------------------------
// Split-K merge for h0/h1 only (h2-7 written directly by attnp).
__global__ __launch_bounds__(256) void attnm_kernel(
    const u16* __restrict__ Opart, const float* __restrict__ ml,
    u16* __restrict__ ob)
{
    const int bid = blockIdx.x;
    const int b = bid / 48;
    const int rr = bid % 48;
    int hh, qc, C, nkc, slot0;
    if (rr < 32) { hh = 0; qc = rr;      C = 2048; nkc = 4; slot0 = b * 192 + qc * 4; }
    else         { hh = 1; qc = rr - 32; C = 1024; nkc = 2; slot0 = b * 192 + 128 + qc * 2; }

    const int tid = threadIdx.x;
    const int r = tid >> 2, cg = (tid & 3) * 16;

    float m[4], li[4];
    float M = -INFINITY;
    for (int i = 0; i < nkc; ++i) {
        m[i]  = ml[(size_t)(slot0 + i) * 128 + r];
        li[i] = ml[(size_t)(slot0 + i) * 128 + 64 + r];
        M = fmaxf(M, m[i]);
    }
    if (C < NSEQ) M = fmaxf(M, 0.0f);
    float L = (C < NSEQ) ? (float)(NSEQ - C) * __expf(-M) : 0.0f;
    float wgt[4];
    for (int i = 0; i < nkc; ++i) {
        wgt[i] = __expf(m[i] - M);
        L += li[i] * wgt[i];
    }
    const float inv = 1.0f / L;

    float o[16];
    #pragma unroll
    for (int j = 0; j < 16; ++j) o[j] = 0.0f;
    for (int i = 0; i < nkc; ++i) {
        const u16* p = Opart + ((size_t)(slot0 + i) * 64 + r) * 64 + cg;
        uint4 v0 = *(const uint4*)(p);
        uint4 v1 = *(const uint4*)(p + 8);
        const u16* pv0 = (const u16*)&v0;
        const u16* pv1 = (const u16*)&v1;
        #pragma unroll
        for (int j = 0; j < 8; ++j) {
            o[j]     += wgt[i] * bf2f(pv0[j]);
            o[8 + j] += wgt[i] * bf2f(pv1[j]);
        }
    }
    u16* obp = ob + ((size_t)b * NSEQ + qc * 64 + r) * DMODEL + hh * 64 + cg;
    #pragma unroll
    for (int j = 0; j < 16; ++j) obp[j] = f2bf(o[j] * inv);
}

// ---------------------------------------------------------------------------
extern "C" void kernel_launch(void* const* d_in, const int* in_sizes, int n_in,
                              void* d_out, int out_size, void* d_ws, size_t ws_size,
                              hipStream_t stream)
{
    (void)in_sizes; (void)n_in; (void)out_size; (void)ws_size;
    const void* x    = d_in[0];
    const void* r_w  = d_in[1];
    const void* r_b  = d_in[2];
    const void* g1   = d_in[3];
    const void* b1   = d_in[4];
    const void* g2   = d_in[5];
    const void* b2   = d_in[6];
    const void* wqkv = d_in[7];
    const void* wo   = d_in[8];
    const void* bo   = d_in[9];
    const void* w1   = d_in[10];
    const void* b1f  = d_in[11];
    const void* w2   = d_in[12];
    const void* b2f  = d_in[13];
    const void* alp  = d_in[14];

    // Workspace overlay (~63.3 MB), all intermediates in COMPACTED order:
    //   [0,8M)    hC / hmC (bf16); dead after ggemm<2> -> Part (fp32, 8MB)
    //   [8M,32M)  qkvC (bf16); later zC (fp32) @ [8M,24M)
    //   [24M,56M) hidC (bf16) — LIVE during ggemm<3>
    //   [32M,40M) obC (bf16)
    //   [40M,48M) Opart (768 slots x 8KB; only h0/h1 slots written)
    //   [48M,56M) VT (live during attnp)
    //   [56M,62M) bf16 transposed weights
    //   [62M,63M) ml (768 x 128 fp32)
    //   [63M,..)  meta
    const size_t MB = 1024 * 1024;
    char* ws = (char*)d_ws;
    u16*   hC     = (u16*)  (ws);
    u16*   hmC    = (u16*)  (ws);
    float* Part   = (float*)(ws);                           // ggemm<3> partials (8MB)
    u16*   qkvC   = (u16*)  (ws + 8 * MB);
    float* zC     = (float*)(ws + 8 * MB);
    u16*   hidC   = (u16*)  (ws + 24 * MB);
    u16*   obC    = (u16*)  (ws + 32 * MB);
    u16*   Opart  = (u16*)  (ws + 40 * MB);                 // 768 slots x 8KB
    u16*   VT     = (u16*)  (ws + 48 * MB);                 // [B*8*64][2048]
    u16*   wqkvT  = (u16*)  (ws + 56 * MB);                 // [1536][512]
    u16*   woT    = (u16*)  (ws + 56 * MB + 1572864);       // [512][512]
    u16*   w1T    = (u16*)  (ws + 56 * MB + 2097152);       // [2048][512]
    u16*   w2T    = (u16*)  (ws + 56 * MB + 4194304);       // [512][2048]
    float* mlbuf  = (float*)(ws + 62 * MB);                 // 768 x 128 fp32
    int*   dtok   = (int*)  (ws + 63 * MB + 1024);
    float* rpw    = (float*)(ws + 63 * MB + 1024 + 32768);
    float* probs  = (float*)(ws + 63 * MB + 1024 + 65536);          // [TOK][4]
    u16*   sorted = (u16*)  (ws + 63 * MB + 1024 + 65536 + 131072); // [B][3][2048]
    int*   perm   = (int*)  (ws + 63 * MB + 1024 + 65536 + 131072 + 49152);
    int*   posOf  = (int*)  (ws + 63 * MB + 1024 + 65536 + 131072 + 49152 + 32768);

    wconv_all_kernel<<<3072, 256, 0, stream>>>(wqkv, wo, w1, w2,
                                               wqkvT, woT, w1T, w2T);
    rprob_kernel<<<TOK / 4, 256, 0, stream>>>(x, r_w, r_b, probs);
    rsort_kernel<<<BATCH * 3, 1024, 0, stream>>>(probs, sorted);
    rassign_kernel<<<BATCH, 1024, 0, stream>>>(probs, sorted, dtok, rpw,
                                               perm, posOf, d_out);
    ln_kernel<0><<<TOK, 256, 0, stream>>>(x, g1, b1, perm, hC);
    ggemm_kernel<0><<<BATCH * 120, 256, 0, stream>>>(
        hC, wqkvT, nullptr, perm, nullptr, nullptr, nullptr, nullptr, nullptr,
        qkvC, nullptr, 1536, 512);
    vtrans_kernel<<<dim3(NSEQ / 64, BATCH * 8), 256, 0, stream>>>(qkvC, VT);
    attnp_kernel<<<BATCH * 192, 256, 0, stream>>>(qkvC, VT, Opart, mlbuf, obC);
    attnm_kernel<<<BATCH * 48, 256, 0, stream>>>(Opart, mlbuf, obC);
    ggemm_kernel<1><<<BATCH * 128, 256, 0, stream>>>(
        obC, woT, bo, perm, nullptr, x, nullptr, nullptr, nullptr,
        nullptr, zC, 512, 512);
    ln_kernel<1><<<TOK, 256, 0, stream>>>(zC, g2, b2, perm, hmC);
    ggemm_kernel<2><<<BATCH * 160, 256, 0, stream>>>(
        hmC, w1T, b1f, perm, nullptr, nullptr, nullptr, nullptr, nullptr,
        hidC, nullptr, 2048, 512);
    ggemm_kernel<3><<<BATCH * 88, 256, 0, stream>>>(
        hidC, w2T, b2f, perm, rpw, nullptr, zC, alp, Part,
        d_out, nullptr, 512, 2048);
    gredfill_kernel<<<BATCH * 2048, 256, 0, stream>>>(
        Part, b2f, rpw, perm, zC, alp, d_out);
}

// Round 21
// 167.841 us; speedup vs baseline: 1.2455x; 1.0030x over previous
//
#include <hip/hip_runtime.h>

typedef unsigned short u16;
typedef unsigned long long u64;

#define BATCH  4
#define NSEQ   2048
#define DMODEL 512
#define TOK    8192   // BATCH*NSEQ

typedef __attribute__((ext_vector_type(8))) __bf16 bf16x8;
typedef __attribute__((ext_vector_type(4))) float f32x4;

__device__ __forceinline__ float bf2f(u16 u) {
    unsigned int x = ((unsigned int)u) << 16;
    return __uint_as_float(x);
}
__device__ __forceinline__ u16 f2bf(float f) {
    unsigned int x = __float_as_uint(f);
    unsigned int r = (x + 0x7FFFu + ((x >> 16) & 1u)) >> 16;  // RNE
    return (u16)r;
}
// IO is fp32 (confirmed rounds 3-20; harness input npz is immutable fp32)
__device__ __forceinline__ float ldf(const void* p, size_t i) {
    return ((const float*)p)[i];
}
__device__ __forceinline__ void stf(void* p, size_t i, float v) {
    ((float*)p)[i] = v;
}
// nested dim for compacted position p within a batch (groups e3|e2|e1|e0)
__device__ __forceinline__ int dt_of_pos(int p) {
    return (p < 256) ? 512 : (p < 512) ? 256 : (p < 1024) ? 128 : 64;
}

// ---------------------------------------------------------------------------
// Fused weight convert + transpose for all 4 weights: in [K][N] -> bf16 [N][K].
__global__ __launch_bounds__(256) void wconv_all_kernel(
    const void* __restrict__ wqkv, const void* __restrict__ wo,
    const void* __restrict__ w1, const void* __restrict__ w2,
    u16* __restrict__ outq, u16* __restrict__ outo,
    u16* __restrict__ out1, u16* __restrict__ out2)
{
    __shared__ float t[32][33];
    int i = blockIdx.x;
    const void* in; u16* out; int K, N, kb, nb;
    if (i < 768)       { in = wqkv; out = outq; K = 512;  N = 1536; kb = (i & 15) * 32; nb = (i >> 4) * 32; }
    else if (i < 1024) { i -= 768;  in = wo; out = outo; K = 512;  N = 512;  kb = (i & 15) * 32; nb = (i >> 4) * 32; }
    else if (i < 2048) { i -= 1024; in = w1; out = out1; K = 512;  N = 2048; kb = (i & 15) * 32; nb = (i >> 4) * 32; }
    else               { i -= 2048; in = w2; out = out2; K = 2048; N = 512;  kb = (i & 63) * 32; nb = (i >> 6) * 32; }
    const int tx = threadIdx.x & 7, ty = threadIdx.x >> 3;
    #pragma unroll
    for (int j = 0; j < 4; ++j)
        t[ty][tx * 4 + j] = ldf(in, (size_t)(kb + ty) * N + nb + tx * 4 + j);
    __syncthreads();
    #pragma unroll
    for (int j = 0; j < 4; ++j)
        out[(size_t)(nb + ty) * K + kb + tx * 4 + j] = f2bf(t[tx * 4 + j][ty]);
}

// ---------------------------------------------------------------------------
// Router phase A: fp64 logits + softmax, one wave per token.
__global__ __launch_bounds__(256) void rprob_kernel(
    const void* __restrict__ xg, const void* __restrict__ rw, const void* __restrict__ rb,
    float* __restrict__ probs)
{
    __shared__ float srw[DMODEL * 4];
    for (int i = threadIdx.x; i < DMODEL * 4; i += 256) srw[i] = ldf(rw, i);
    __syncthreads();
    const int w = threadIdx.x >> 6, l = threadIdx.x & 63;
    const int t = blockIdx.x * 4 + w;
    double a0 = (double)ldf(rb, 0), a1 = (double)ldf(rb, 1);
    double a2 = (double)ldf(rb, 2), a3 = (double)ldf(rb, 3);
    const size_t xbase = (size_t)t * DMODEL + l * 8;
    #pragma unroll
    for (int j = 0; j < 8; ++j) {
        double xv = (double)ldf(xg, xbase + j);
        int d = l * 8 + j;
        a0 += xv * (double)srw[d * 4 + 0];
        a1 += xv * (double)srw[d * 4 + 1];
        a2 += xv * (double)srw[d * 4 + 2];
        a3 += xv * (double)srw[d * 4 + 3];
    }
    #pragma unroll
    for (int off = 32; off > 0; off >>= 1) {
        a0 += __shfl_xor(a0, off);
        a1 += __shfl_xor(a1, off);
        a2 += __shfl_xor(a2, off);
        a3 += __shfl_xor(a3, off);
    }
    if (l == 0) {
        double mx = fmax(fmax(a0, a1), fmax(a2, a3));
        double e0 = exp(a0 - mx), e1 = exp(a1 - mx), e2 = exp(a2 - mx), e3 = exp(a3 - mx);
        double s = e0 + e1 + e2 + e3;
        float4 p = make_float4((float)(e0 / s), (float)(e1 / s),
                               (float)(e2 / s), (float)(e3 / s));
        *reinterpret_cast<float4*>(probs + (size_t)t * 4) = p;
    }
}

// ---------------------------------------------------------------------------
// Router phase B: per (batch, expert e=3,2,1) bitonic sort of u64 keys
// ((probbits<<32) | (2047-idx)) descending == (prob desc, idx asc).
__global__ __launch_bounds__(1024) void rsort_kernel(
    const float* __restrict__ probs, u16* __restrict__ sortedIdx)
{
    __shared__ u64 sk[NSEQ];   // 16 KB
    const int bid = blockIdx.x;
    const int b = bid / 3, ei = bid % 3, e = 3 - ei;
    const int tid = threadIdx.x;
    for (int n = tid; n < NSEQ; n += 1024) {
        unsigned fb = __float_as_uint(probs[((size_t)b * NSEQ + n) * 4 + e]);
        sk[n] = ((u64)fb << 32) | (unsigned)(2047 - n);
    }
    for (unsigned k = 2; k <= NSEQ; k <<= 1) {
        for (unsigned j = k >> 1; j > 0; j >>= 1) {
            __syncthreads();
            unsigned i = ((tid & ~(j - 1)) << 1) | (tid & (j - 1));
            unsigned ixj = i | j;
            u64 a = sk[i], c = sk[ixj];
            bool up = ((i & k) == 0);
            if ((a < c) == up) { sk[i] = c; sk[ixj] = a; }
        }
    }
    __syncthreads();
    u16* out = sortedIdx + ((size_t)b * 3 + ei) * NSEQ;
    for (int n = tid; n < NSEQ; n += 1024)
        out[n] = (u16)(2047u - (unsigned)(sk[n] & 0xFFFFFFFFu));
}

// ---------------------------------------------------------------------------
// Router phase C: greedy capacity selection per batch (e=3,2,1; leftovers->0),
// emit rpw/outputs and the expert-sorted permutation perm.
__global__ __launch_bounds__(1024) void rassign_kernel(
    const float* __restrict__ probs, const u16* __restrict__ sortedIdx,
    float* __restrict__ rpw, int* __restrict__ perm, void* __restrict__ outp)
{
    __shared__ int sassigned[NSEQ];   // 8 KB
    __shared__ int wsum[16];
    const int b = blockIdx.x;
    const int tid = threadIdx.x;
    const int lane = tid & 63;
    for (int n = tid; n < NSEQ; n += 1024) sassigned[n] = -1;
    __syncthreads();
    const int caps[3] = {256, 256, 512};   // e = 3, 2, 1
    #pragma unroll
    for (int ei = 0; ei < 3; ++ei) {
        const int e = 3 - ei, cap = caps[ei];
        const u16* sl = sortedIdx + ((size_t)b * 3 + ei) * NSEQ;
        int t0 = sl[2 * tid], t1 = sl[2 * tid + 1];
        int f0 = (sassigned[t0] < 0) ? 1 : 0;
        int f1 = (sassigned[t1] < 0) ? 1 : 0;
        int s = f0 + f1;
        #pragma unroll
        for (int off = 1; off < 64; off <<= 1) {
            int v = __shfl_up(s, off);
            if (lane >= off) s += v;
        }
        if (lane == 63) wsum[tid >> 6] = s;
        __syncthreads();
        if (tid < 16) {
            int v = wsum[tid];
            #pragma unroll
            for (int off = 1; off < 16; off <<= 1) {
                int u = __shfl_up(v, off);
                if (tid >= off) v += u;
            }
            wsum[tid] = v;
        }
        __syncthreads();
        int wprev = (tid >> 6) ? wsum[(tid >> 6) - 1] : 0;
        int excl0 = s + wprev - f0 - f1;   // rank of t0 among unassigned
        if (f0 && excl0 < cap) sassigned[t0] = e;
        if (f1 && excl0 + f0 < cap) sassigned[t1] = e;
        __syncthreads();
    }
    // leftovers -> expert 0
    for (int n = tid; n < NSEQ; n += 1024)
        if (sassigned[n] < 0) sassigned[n] = 0;
    __syncthreads();
    // stable perm: for each expert, block-scan rank in ascending token order
    #pragma unroll
    for (int e = 0; e < 4; ++e) {
        const int n0 = 2 * tid, n1 = 2 * tid + 1;
        const int f0 = (sassigned[n0] == e) ? 1 : 0;
        const int f1 = (sassigned[n1] == e) ? 1 : 0;
        int s = f0 + f1;
        #pragma unroll
        for (int off = 1; off < 64; off <<= 1) {
            int v = __shfl_up(s, off);
            if (lane >= off) s += v;
        }
        if (lane == 63) wsum[tid >> 6] = s;
        __syncthreads();
        if (tid < 16) {
            int v = wsum[tid];
            #pragma unroll
            for (int off = 1; off < 16; off <<= 1) {
                int u = __shfl_up(v, off);
                if (tid >= off) v += u;
            }
            wsum[tid] = v;
        }
        __syncthreads();
        int wprev = (tid >> 6) ? wsum[(tid >> 6) - 1] : 0;
        int rank0 = s + wprev - f0 - f1;
        const int offe = (e == 3) ? 0 : (e == 2) ? 256 : (e == 1) ? 512 : 1024;
        if (f0) perm[b * NSEQ + offe + rank0] = n0;
        if (f1) perm[b * NSEQ + offe + rank0 + f0] = n1;
        __syncthreads();
    }
    const size_t base0 = (size_t)TOK * DMODEL;
    for (int n = tid; n < NSEQ; n += 1024) {
        int e = sassigned[n];
        size_t g = (size_t)b * NSEQ + n;
        float rpv = probs[g * 4 + e];
        rpw[g] = rpv;
        stf(outp, base0 + g, (float)e);
        stf(outp, base0 + TOK + g, rpv);
    }
}

// ---------------------------------------------------------------------------
// LayerNorm in COMPACTED order. Block row = compacted position.
// INMODE 0: input x (fp32), gathered via perm. INMODE 1: input zC fp32.
template <int INMODE>
__global__ __launch_bounds__(256) void ln_kernel(
    const void* __restrict__ in, const void* __restrict__ gw, const void* __restrict__ bw,
    const int* __restrict__ perm, u16* __restrict__ out)
{
    const int row = blockIdx.x;            // compacted global row
    const int tid = threadIdx.x;
    size_t srow;
    if (INMODE == 0) {
        srow = (size_t)(row & ~(NSEQ - 1)) + perm[row];
    } else {
        srow = (size_t)row;
    }
    size_t base = srow * DMODEL + tid * 2;
    float2 t = *(const float2*)((const float*)in + base);
    float x0 = t.x, x1 = t.y;
    float s = x0 + x1;
    #pragma unroll
    for (int d2 = 32; d2 > 0; d2 >>= 1) s += __shfl_down(s, d2);
    __shared__ float red[4];
    if ((tid & 63) == 0) red[tid >> 6] = s;
    __syncthreads();
    s = red[0] + red[1] + red[2] + red[3];
    float mu = s * (1.0f / DMODEL);
    float d0 = x0 - mu, d1 = x1 - mu;
    float q2 = d0 * d0 + d1 * d1;
    #pragma unroll
    for (int d2 = 32; d2 > 0; d2 >>= 1) q2 += __shfl_down(q2, d2);
    __syncthreads();
    if ((tid & 63) == 0) red[tid >> 6] = q2;
    __syncthreads();
    q2 = red[0] + red[1] + red[2] + red[3];
    float inv = rsqrtf(q2 * (1.0f / DMODEL) + 1e-5f);
    const int dt = dt_of_pos(row & (NSEQ - 1));
    int j0 = tid * 2;
    float r0 = (j0 < dt)     ? (d0 * inv * ldf(gw, j0)     + ldf(bw, j0))     : 0.0f;
    float r1 = (j0 + 1 < dt) ? (d1 * inv * ldf(gw, j0 + 1) + ldf(bw, j0 + 1)) : 0.0f;
    u16* op = out + (size_t)row * DMODEL + j0;
    op[0] = f2bf(r0); op[1] = f2bf(r1);
}

// ---------------------------------------------------------------------------
__device__ __forceinline__ float gelu_tanh(float x) {
    float x3 = x * x * x;
    float t = tanhf(0.7978845608028654f * (x + 0.044715f * x3));
    return 0.5f * x * (1.0f + t);
}

// Group-sparse MFMA GEMM over expert-compacted rows. Per-batch groups
// (e3:256 rows dt=512 | e2:256 dt=256 | e1:512 dt=128 | e0:1024 dt=64).
// 128x64 tiles. Double-buffered LDS, one barrier per K-step; staging regs
// transient within an iteration (rounds 7/11 spill lesson).
// MODE 0: hC@dt  x wqkvT -> qkvC, N tiles = 3 slices x dt          (K=dt)
// MODE 1: obC@dt x woT   -> zC = v_masked + x[perm],  N full 512   (K=dt)
// MODE 2: hmC@dt x w1T   -> hidC = gelu(+bias), N tiles = 4dt      (K=dt)
// MODE 3: hidC   x w2T   -> g3 ONLY split-K kc=4 -> fp32 partials in Part;
//          g2/g1/g0 full epilogue in-kernel (K=4dt).
template <int MODE>
__global__ __launch_bounds__(256, 2) void ggemm_kernel(
    const u16* __restrict__ A, const u16* __restrict__ Bt, const void* __restrict__ bias,
    const int* __restrict__ perm, const float* __restrict__ rp,
    const void* __restrict__ resx, const float* __restrict__ resz, const void* __restrict__ alp,
    float* __restrict__ Part,
    void* __restrict__ C, float* __restrict__ Cz, int Ncols, int Kdim)
{
    constexpr int T = (MODE == 0) ? 120 : (MODE == 1) ? 128 : (MODE == 2) ? 160 : 88;
    __shared__ u16 As[2][128][72];   // 36 KB
    __shared__ u16 Bs[2][64][72];    // 18 KB
    const int tid = threadIdx.x;
    const int w = tid >> 6, l = tid & 63, ln = l & 15, lg = l >> 4;
    const int wr = w >> 1, wc = w & 1;

    // decode (batch, group g, mtile, ntile, kchunk)
    const int batch = blockIdx.x / T;
    int r = blockIdx.x % T;
    int g = 3, mt = 0, nt = 0, kc = 0;
    #pragma unroll
    for (int gg = 3; gg >= 0; --gg) {
        const int NTg = (MODE == 0) ? 3 * (1 << gg) : (MODE == 1) ? 8
                       : (MODE == 2) ? (4 << gg) : (1 << gg);
        const int MTg = (gg == 0) ? 8 : (gg == 1) ? 4 : 2;
        const int KCg = (MODE == 3 && gg == 3) ? 4 : 1;
        const int cnt = MTg * NTg * KCg;
        if (r >= 0 && r < cnt) {
            g = gg; mt = r / (NTg * KCg);
            int rem = r % (NTg * KCg);
            nt = rem / KCg; kc = rem % KCg;
        }
        r -= cnt;
    }
    const int dtg = 64 << g;
    const int offg = (g == 3) ? 0 : (g == 2) ? 256 : (g == 1) ? 512 : 1024;
    const int rowbase = batch * NSEQ + offg + mt * 128;
    int c0;
    if (MODE == 0) {
        const int per = 1 << g;                 // dt/64
        c0 = (nt / per) * DMODEL + (nt % per) * 64;
    } else {
        c0 = nt * 64;
    }
    const int Keff = (MODE == 3) ? 4 * dtg : dtg;
    const int KCg = (MODE == 3 && g == 3) ? 4 : 1;
    const int Klen = Keff / KCg;
    const int kbeg = kc * Klen;

    f32x4 acc[4][2];
    #pragma unroll
    for (int mi = 0; mi < 4; ++mi) {
        acc[mi][0] = f32x4{0.f, 0.f, 0.f, 0.f};
        acc[mi][1] = f32x4{0.f, 0.f, 0.f, 0.f};
    }

    const int sr = tid >> 1, sc0 = (tid & 1) * 32;   // A staging
    const int br = tid >> 2, bc0 = (tid & 3) * 16;   // B staging
    auto stage = [&](int k0, int buf) {
        const u16* srcA = A + (size_t)(rowbase + sr) * Kdim + k0 + sc0;
        uint4 a0 = *(const uint4*)(srcA);
        uint4 a1 = *(const uint4*)(srcA + 8);
        uint4 a2 = *(const uint4*)(srcA + 16);
        uint4 a3 = *(const uint4*)(srcA + 24);
        *(uint4*)&As[buf][sr][sc0]      = a0;
        *(uint4*)&As[buf][sr][sc0 + 8]  = a1;
        *(uint4*)&As[buf][sr][sc0 + 16] = a2;
        *(uint4*)&As[buf][sr][sc0 + 24] = a3;
        const u16* srcB = Bt + (size_t)(c0 + br) * Kdim + k0 + bc0;
        uint4 b0 = *(const uint4*)(srcB);
        uint4 b1 = *(const uint4*)(srcB + 8);
        *(uint4*)&Bs[buf][br][bc0]     = b0;
        *(uint4*)&Bs[buf][br][bc0 + 8] = b1;
    };

    stage(kbeg, 0);
    int cur = 0;
    for (int k0 = kbeg; k0 < kbeg + Klen; k0 += 64) {
        __syncthreads();
        if (k0 + 64 < kbeg + Klen) stage(k0 + 64, cur ^ 1);
        bf16x8 fb[2][2];
        #pragma unroll
        for (int ci = 0; ci < 2; ++ci)
            #pragma unroll
            for (int ks = 0; ks < 2; ++ks)
                fb[ci][ks] = *reinterpret_cast<const bf16x8*>(
                    &Bs[cur][wc * 32 + ci * 16 + ln][ks * 32 + lg * 8]);
        __builtin_amdgcn_s_setprio(1);
        #pragma unroll
        for (int mi = 0; mi < 4; ++mi) {
            bf16x8 fa0 = *reinterpret_cast<const bf16x8*>(
                &As[cur][wr * 64 + mi * 16 + ln][lg * 8]);
            bf16x8 fa1 = *reinterpret_cast<const bf16x8*>(
                &As[cur][wr * 64 + mi * 16 + ln][32 + lg * 8]);
            #pragma unroll
            for (int ci = 0; ci < 2; ++ci) {
                acc[mi][ci] = __builtin_amdgcn_mfma_f32_16x16x32_bf16(fa0, fb[ci][0], acc[mi][ci], 0, 0, 0);
                acc[mi][ci] = __builtin_amdgcn_mfma_f32_16x16x32_bf16(fa1, fb[ci][1], acc[mi][ci], 0, 0, 0);
            }
        }
        __builtin_amdgcn_s_setprio(0);
        cur ^= 1;
    }

    // MODE 3 g3: raw fp32 partial (bias/gate/z applied in greduce)
    if (MODE == 3 && KCg > 1) {
        const int slot = (mt * 8 + nt) * 4 + kc;     // 0..63
        float* pp = Part + ((size_t)(batch * 64 + slot) * 128) * 64;
        #pragma unroll
        for (int mi = 0; mi < 4; ++mi)
            #pragma unroll
            for (int rr = 0; rr < 4; ++rr) {
                const int lrow = wr * 64 + mi * 16 + 4 * lg + rr;
                #pragma unroll
                for (int ci = 0; ci < 2; ++ci)
                    pp[lrow * 64 + wc * 32 + ci * 16 + ln] = acc[mi][ci][rr];
            }
        return;
    }

    const float alphav = (MODE == 3) ? ldf(alp, 0) : 0.0f;
    #pragma unroll
    for (int mi = 0; mi < 4; ++mi) {
        #pragma unroll
        for (int rr = 0; rr < 4; ++rr) {
            const int row = rowbase + wr * 64 + mi * 16 + 4 * lg + rr;
            #pragma unroll
            for (int ci = 0; ci < 2; ++ci) {
                const int c = c0 + wc * 32 + ci * 16 + ln;
                float v = acc[mi][ci][rr];
                if (MODE == 0) {
                    ((u16*)C)[(size_t)row * Ncols + c] = f2bf(v);
                } else if (MODE == 1) {
                    v += ldf(bias, c);
                    if (c >= dtg) v = 0.0f;
                    const size_t xrow = (size_t)(row & ~(NSEQ - 1)) + perm[row];
                    v += ldf(resx, xrow * DMODEL + c);
                    Cz[(size_t)row * DMODEL + c] = v;
                } else if (MODE == 2) {
                    v += ldf(bias, c);
                    ((u16*)C)[(size_t)row * Ncols + c] = f2bf(gelu_tanh(v));
                } else {
                    v += ldf(bias, c);
                    const size_t orow = (size_t)(row & ~(NSEQ - 1)) + perm[row];
                    const float gate = 1.0f + alphav * rp[orow];
                    float outv = resz[(size_t)row * DMODEL + c] + gate * v;
                    stf(C, orow * DMODEL + c, outv);
                }
            }
        }
    }
}

// ---------------------------------------------------------------------------
// Combined split-K reduce (g3 rows, pos<256) + fill pass (pos>=256):
// one block per (batch, compacted pos).
__global__ __launch_bounds__(256) void gredfill_kernel(
    const float* __restrict__ Part, const void* __restrict__ bias,
    const float* __restrict__ rp, const int* __restrict__ perm,
    const float* __restrict__ zC, const void* __restrict__ alp,
    void* __restrict__ outp)
{
    const int b = blockIdx.x >> 11;         // / 2048
    const int pos = blockIdx.x & 2047;
    const int row = b * NSEQ + pos;
    const size_t orow = (size_t)b * NSEQ + perm[row];
    if (pos < 256) {
        const int mt = pos >> 7, rowIn = pos & 127;
        const float alphav = ldf(alp, 0);
        const float gate = 1.0f + alphav * rp[orow];
        for (int c = threadIdx.x; c < DMODEL; c += 256) {
            const int nt = c >> 6, col = c & 63;
            const int slot0 = (mt * 8 + nt) * 4;
            float v = 0.0f;
            #pragma unroll
            for (int i = 0; i < 4; ++i)
                v += Part[((size_t)(b * 64 + slot0 + i) * 128 + rowIn) * 64 + col];
            v += ldf(bias, c);
            float outv = zC[(size_t)row * DMODEL + c] + gate * v;
            stf(outp, orow * DMODEL + c, outv);
        }
    } else {
        const int dt = dt_of_pos(pos);
        for (int c = dt + threadIdx.x; c < DMODEL; c += 256)
            stf(outp, orow * DMODEL + c, zC[(size_t)row * DMODEL + c]);
    }
}

// ---------------------------------------------------------------------------
// V transpose: qkvC (compacted) V-slice -> VT[(b*8+h)*64 + d][NSEQ pos].
__global__ __launch_bounds__(256) void vtrans_kernel(
    const u16* __restrict__ qkvC, u16* __restrict__ VT)
{
    __shared__ u16 tl[64][72];
    const int bh = blockIdx.y, b = bh >> 3, hh = bh & 7;
    const int k0 = blockIdx.x * 64;
    const int tid = threadIdx.x;
    #pragma unroll
    for (int p = 0; p < 2; ++p) {
        int idx = p * 256 + tid;
        int row = idx >> 3, c8 = (idx & 7) * 8;
        uint4 v = *(const uint4*)(qkvC + ((size_t)b * NSEQ + k0 + row) * 1536
                                  + 1024 + hh * 64 + c8);
        const u16* pv = (const u16*)&v;
        #pragma unroll
        for (int j = 0; j < 8; ++j) tl[c8 + j][row] = pv[j];
    }
    __syncthreads();
    #pragma unroll
    for (int p = 0; p < 2; ++p) {
        int idx = p * 256 + tid;
        int d = idx >> 3, k8 = (idx & 7) * 8;
        uint4 o = *(const uint4*)&tl[d][k8];
        *(uint4*)(VT + ((size_t)bh * 64 + d) * NSEQ + k0 + k8) = o;
    }
}

// ---------------------------------------------------------------------------
// Split-K flash attention, phase 1. Round-15 split (512-key chunks): per batch
// 192 slots — h0: qc*4+kc | h1: 128+qc*2+kc | h2: 160+qc | h3: 168+qc |
// h4-7: 176+(h-4)*4+qc. Heads h2..h7 (nkc==1) normalize in-kernel and write
// obC directly; h0/h1 emit partials. Double-buffered K/V LDS, one barrier/tile.
__global__ __launch_bounds__(256, 2) void attnp_kernel(
    const u16* __restrict__ qkvC, const u16* __restrict__ VT,
    u16* __restrict__ Opart, float* __restrict__ ml, u16* __restrict__ ob)
{
    __shared__ u16 Ks[2][64 * 72];   // 18 KB
    __shared__ u16 Vs[2][64 * 72];   // 18 KB (transposed: Vs[d][key])
    __shared__ u16 Ps[4 * 16 * 72];  //  9 KB

    const int bid = blockIdx.x;
    const int b = bid / 192;
    const int rr = bid % 192;
    int hh, qc, kc, C;
    if (rr < 128)      { hh = 0; qc = rr >> 2;        kc = rr & 3; C = 2048; }
    else if (rr < 160) { int t = rr - 128; hh = 1; qc = t >> 1; kc = t & 1; C = 1024; }
    else if (rr < 168) { hh = 2; qc = rr - 160; kc = 0; C = 512; }
    else if (rr < 176) { hh = 3; qc = rr - 168; kc = 0; C = 512; }
    else { int t = rr - 176; hh = 4 + (t >> 2); qc = t & 3; kc = 0; C = 256; }
    const int k_beg = kc * 512;
    const int k_end = (k_beg + 512 < C) ? (k_beg + 512) : C;

    const int tid = threadIdx.x;
    const int w = tid >> 6, l = tid & 63;
    const int ln = l & 15, lg = l >> 4;

    const size_t bbase = (size_t)b * NSEQ;
    const int q0 = qc * 64 + w * 16;

    bf16x8 qa[2];
    {
        const u16* qrow = qkvC + (bbase + q0 + ln) * 1536 + hh * 64;
        #pragma unroll
        for (int s = 0; s < 2; ++s) {
            bf16x8 t = *reinterpret_cast<const bf16x8*>(qrow + 8 * lg + 32 * s);
            #pragma unroll
            for (int j = 0; j < 8; ++j) t[j] = (__bf16)((float)t[j] * 0.125f);
            qa[s] = t;
        }
    }

    const int srow = tid >> 3, sc8 = (tid & 7) * 8;
    const u16* kbase = qkvC + (bbase + srow) * 1536 + 512 + hh * 64 + sc8;
    const size_t vrowbase = (size_t)(b * 8 + hh) * 64 + srow;
    auto stagea = [&](int t0, int buf) {
        #pragma unroll
        for (int p = 0; p < 2; ++p) {
            int roff = p * 32;
            uint4 kv = *(const uint4*)(kbase + (size_t)(t0 + roff) * 1536);
            uint4 vv = *(const uint4*)(VT + (vrowbase + roff) * NSEQ + t0 + sc8);
            *(uint4*)&Ks[buf][(srow + roff) * 72 + sc8] = kv;
            *(uint4*)&Vs[buf][(srow + roff) * 72 + sc8] = vv;
        }
    };

    f32x4 oacc[4];
    #pragma unroll
    for (int d0 = 0; d0 < 4; ++d0) oacc[d0] = f32x4{0.f, 0.f, 0.f, 0.f};
    float mold[4] = {-INFINITY, -INFINITY, -INFINITY, -INFINITY};
    float lsum[4] = {0.f, 0.f, 0.f, 0.f};
    u16* Pw = Ps + w * 16 * 72;

    stagea(k_beg, 0);
    int cur = 0;
    for (int t0 = k_beg; t0 < k_end; t0 += 64) {
        __syncthreads();
        if (t0 + 64 < k_end) stagea(t0 + 64, cur ^ 1);

        f32x4 sa[4];
        #pragma unroll
        for (int kb = 0; kb < 4; ++kb) sa[kb] = f32x4{0.f, 0.f, 0.f, 0.f};
        __builtin_amdgcn_s_setprio(1);
        #pragma unroll
        for (int kb = 0; kb < 4; ++kb) {
            #pragma unroll
            for (int s = 0; s < 2; ++s) {
                bf16x8 kf = *reinterpret_cast<const bf16x8*>(
                    &Ks[cur][(kb * 16 + ln) * 72 + 8 * lg + 32 * s]);
                sa[kb] = __builtin_amdgcn_mfma_f32_16x16x32_bf16(qa[s], kf, sa[kb], 0, 0, 0);
            }
        }
        __builtin_amdgcn_s_setprio(0);

        float nm[4], sc[4];
        #pragma unroll
        for (int r = 0; r < 4; ++r) {
            float mx = fmaxf(fmaxf(sa[0][r], sa[1][r]), fmaxf(sa[2][r], sa[3][r]));
            mx = fmaxf(mx, __shfl_xor(mx, 1));
            mx = fmaxf(mx, __shfl_xor(mx, 2));
            mx = fmaxf(mx, __shfl_xor(mx, 4));
            mx = fmaxf(mx, __shfl_xor(mx, 8));
            nm[r] = fmaxf(mold[r], mx);
            sc[r] = __expf(mold[r] - nm[r]);
            mold[r] = nm[r];
        }
        float psum[4] = {0.f, 0.f, 0.f, 0.f};
        #pragma unroll
        for (int kb = 0; kb < 4; ++kb) {
            #pragma unroll
            for (int r = 0; r < 4; ++r) {
                float p = __expf(sa[kb][r] - nm[r]);
                psum[r] += p;
                Pw[(4 * lg + r) * 72 + kb * 16 + ln] = f2bf(p);
            }
        }
        #pragma unroll
        for (int r = 0; r < 4; ++r) {
            float s = psum[r];
            s += __shfl_xor(s, 1);
            s += __shfl_xor(s, 2);
            s += __shfl_xor(s, 4);
            s += __shfl_xor(s, 8);
            lsum[r] = lsum[r] * sc[r] + s;
            #pragma unroll
            for (int d0 = 0; d0 < 4; ++d0) oacc[d0][r] *= sc[r];
        }
        asm volatile("s_waitcnt lgkmcnt(0)" ::: "memory");  // P writes visible

        bf16x8 pf[2];
        pf[0] = *reinterpret_cast<const bf16x8*>(&Pw[ln * 72 + 8 * lg]);
        pf[1] = *reinterpret_cast<const bf16x8*>(&Pw[ln * 72 + 8 * lg + 32]);
        __builtin_amdgcn_s_setprio(1);
        #pragma unroll
        for (int d0 = 0; d0 < 4; ++d0) {
            #pragma unroll
            for (int s = 0; s < 2; ++s) {
                bf16x8 vf = *reinterpret_cast<const bf16x8*>(
                    &Vs[cur][(d0 * 16 + ln) * 72 + 8 * lg + 32 * s]);
                oacc[d0] = __builtin_amdgcn_mfma_f32_16x16x32_bf16(pf[s], vf, oacc[d0], 0, 0, 0);
            }
        }
        __builtin_amdgcn_s_setprio(0);
        cur ^= 1;
    }

    if (hh >= 2) {
        // single-chunk heads: normalize + analytic null-key term, write obC
        #pragma unroll
        for (int r = 0; r < 4; ++r) {
            float mf = mold[r];
            float M = fmaxf(mf, 0.0f);           // C < NSEQ always here
            float ec = __expf(mf - M);
            float L = lsum[r] * ec + (float)(NSEQ - C) * __expf(-M);
            float rs = ec / L;
            u16* obp = ob + (bbase + q0 + 4 * lg + r) * DMODEL + hh * 64;
            #pragma unroll
            for (int d0 = 0; d0 < 4; ++d0)
                obp[d0 * 16 + ln] = f2bf(oacc[d0][r] * rs);
        }
        return;
    }

    // h0/h1: write unnormalized partial (row includes wave offset w*16)
    u16* op = Opart + (size_t)bid * 64 * 64;
    #pragma unroll
    for (int r = 0; r < 4; ++r) {
        const int row = w * 16 + 4 * lg + r;
        #pragma unroll
        for (int d0 = 0; d0 < 4; ++d0)
            op[row * 64 + d0 * 16 + ln] = f2bf(oacc[d0][r]);
        if (ln == 0) {
            ml[(size_t)bid * 128 + row] = mold[r];
            ml[(size_t)bid * 128 + 64 + row] = lsum[r];
        }
    }
}

// ---------------------------------------------------------------------------
// Split-K merge for h0/h1 only (h2-7 written directly by attnp).
__global__ __launch_bounds__(256) void attnm_kernel(
    const u16* __restrict__ Opart, const float* __restrict__ ml,
    u16* __restrict__ ob)
{
    const int bid = blockIdx.x;
    const int b = bid / 48;
    const int rr = bid % 48;
    int hh, qc, C, nkc, slot0;
    if (rr < 32) { hh = 0; qc = rr;      C = 2048; nkc = 4; slot0 = b * 192 + qc * 4; }
    else         { hh = 1; qc = rr - 32; C = 1024; nkc = 2; slot0 = b * 192 + 128 + qc * 2; }

    const int tid = threadIdx.x;
    const int r = tid >> 2, cg = (tid & 3) * 16;

    float m[4], li[4];
    float M = -INFINITY;
    for (int i = 0; i < nkc; ++i) {
        m[i]  = ml[(size_t)(slot0 + i) * 128 + r];
        li[i] = ml[(size_t)(slot0 + i) * 128 + 64 + r];
        M = fmaxf(M, m[i]);
    }
    if (C < NSEQ) M = fmaxf(M, 0.0f);
    float L = (C < NSEQ) ? (float)(NSEQ - C) * __expf(-M) : 0.0f;
    float wgt[4];
    for (int i = 0; i < nkc; ++i) {
        wgt[i] = __expf(m[i] - M);
        L += li[i] * wgt[i];
    }
    const float inv = 1.0f / L;

    float o[16];
    #pragma unroll
    for (int j = 0; j < 16; ++j) o[j] = 0.0f;
    for (int i = 0; i < nkc; ++i) {
        const u16* p = Opart + ((size_t)(slot0 + i) * 64 + r) * 64 + cg;
        uint4 v0 = *(const uint4*)(p);
        uint4 v1 = *(const uint4*)(p + 8);
        const u16* pv0 = (const u16*)&v0;
        const u16* pv1 = (const u16*)&v1;
        #pragma unroll
        for (int j = 0; j < 8; ++j) {
            o[j]     += wgt[i] * bf2f(pv0[j]);
            o[8 + j] += wgt[i] * bf2f(pv1[j]);
        }
    }
    u16* obp = ob + ((size_t)b * NSEQ + qc * 64 + r) * DMODEL + hh * 64 + cg;
    #pragma unroll
    for (int j = 0; j < 16; ++j) obp[j] = f2bf(o[j] * inv);
}

// ---------------------------------------------------------------------------
extern "C" void kernel_launch(void* const* d_in, const int* in_sizes, int n_in,
                              void* d_out, int out_size, void* d_ws, size_t ws_size,
                              hipStream_t stream)
{
    (void)in_sizes; (void)n_in; (void)out_size; (void)ws_size;
    const void* x    = d_in[0];
    const void* r_w  = d_in[1];
    const void* r_b  = d_in[2];
    const void* g1   = d_in[3];
    const void* b1   = d_in[4];
    const void* g2   = d_in[5];
    const void* b2   = d_in[6];
    const void* wqkv = d_in[7];
    const void* wo   = d_in[8];
    const void* bo   = d_in[9];
    const void* w1   = d_in[10];
    const void* b1f  = d_in[11];
    const void* w2   = d_in[12];
    const void* b2f  = d_in[13];
    const void* alp  = d_in[14];

    // Workspace overlay (~63.3 MB), all intermediates in COMPACTED order:
    //   [0,8M)    hC / hmC (bf16); dead after ggemm<2> -> Part (fp32, 8MB)
    //   [8M,32M)  qkvC (bf16); later zC (fp32) @ [8M,24M)
    //   [24M,56M) hidC (bf16) — LIVE during ggemm<3>
    //   [32M,40M) obC (bf16)
    //   [40M,48M) Opart (768 slots x 8KB; only h0/h1 slots written)
    //   [48M,56M) VT (live during attnp)
    //   [56M,62M) bf16 transposed weights
    //   [62M,63M) ml (768 x 128 fp32)
    //   [63M,..)  meta
    const size_t MB = 1024 * 1024;
    char* ws = (char*)d_ws;
    u16*   hC     = (u16*)  (ws);
    u16*   hmC    = (u16*)  (ws);
    float* Part   = (float*)(ws);                           // ggemm<3> partials (8MB)
    u16*   qkvC   = (u16*)  (ws + 8 * MB);
    float* zC     = (float*)(ws + 8 * MB);
    u16*   hidC   = (u16*)  (ws + 24 * MB);
    u16*   obC    = (u16*)  (ws + 32 * MB);
    u16*   Opart  = (u16*)  (ws + 40 * MB);                 // 768 slots x 8KB
    u16*   VT     = (u16*)  (ws + 48 * MB);                 // [B*8*64][2048]
    u16*   wqkvT  = (u16*)  (ws + 56 * MB);                 // [1536][512]
    u16*   woT    = (u16*)  (ws + 56 * MB + 1572864);       // [512][512]
    u16*   w1T    = (u16*)  (ws + 56 * MB + 2097152);       // [2048][512]
    u16*   w2T    = (u16*)  (ws + 56 * MB + 4194304);       // [512][2048]
    float* mlbuf  = (float*)(ws + 62 * MB);                 // 768 x 128 fp32
    float* rpw    = (float*)(ws + 63 * MB + 1024 + 32768);
    float* probs  = (float*)(ws + 63 * MB + 1024 + 65536);          // [TOK][4]
    u16*   sorted = (u16*)  (ws + 63 * MB + 1024 + 65536 + 131072); // [B][3][2048]
    int*   perm   = (int*)  (ws + 63 * MB + 1024 + 65536 + 131072 + 49152);

    wconv_all_kernel<<<3072, 256, 0, stream>>>(wqkv, wo, w1, w2,
                                               wqkvT, woT, w1T, w2T);
    rprob_kernel<<<TOK / 4, 256, 0, stream>>>(x, r_w, r_b, probs);
    rsort_kernel<<<BATCH * 3, 1024, 0, stream>>>(probs, sorted);
    rassign_kernel<<<BATCH, 1024, 0, stream>>>(probs, sorted, rpw, perm, d_out);
    ln_kernel<0><<<TOK, 256, 0, stream>>>(x, g1, b1, perm, hC);
    ggemm_kernel<0><<<BATCH * 120, 256, 0, stream>>>(
        hC, wqkvT, nullptr, perm, nullptr, nullptr, nullptr, nullptr, nullptr,
        qkvC, nullptr, 1536, 512);
    vtrans_kernel<<<dim3(NSEQ / 64, BATCH * 8), 256, 0, stream>>>(qkvC, VT);
    attnp_kernel<<<BATCH * 192, 256, 0, stream>>>(qkvC, VT, Opart, mlbuf, obC);
    attnm_kernel<<<BATCH * 48, 256, 0, stream>>>(Opart, mlbuf, obC);
    ggemm_kernel<1><<<BATCH * 128, 256, 0, stream>>>(
        obC, woT, bo, perm, nullptr, x, nullptr, nullptr, nullptr,
        nullptr, zC, 512, 512);
    ln_kernel<1><<<TOK, 256, 0, stream>>>(zC, g2, b2, perm, hmC);
    ggemm_kernel<2><<<BATCH * 160, 256, 0, stream>>>(
        hmC, w1T, b1f, perm, nullptr, nullptr, nullptr, nullptr, nullptr,
        hidC, nullptr, 2048, 512);
    ggemm_kernel<3><<<BATCH * 88, 256, 0, stream>>>(
        hidC, w2T, b2f, perm, rpw, nullptr, zC, alp, Part,
        d_out, nullptr, 512, 2048);
    gredfill_kernel<<<BATCH * 2048, 256, 0, stream>>>(
        Part, b2f, rpw, perm, zC, alp, d_out);
}